// Round 1
// baseline (4968.859 us; speedup 1.0000x reference)
//
#include <hip/hip_runtime.h>
#include <math.h>

#define EPS 1e-5f

__device__ __forceinline__ float sigmoidf_(float x){ return 1.f/(1.f+__expf(-x)); }

// block-wide reduction of two accumulators; blockDim.x must be a multiple of 64
__device__ __forceinline__ void block_reduce2(float& s, float& s2){
  __shared__ float ls[16], ls2[16];
  #pragma unroll
  for (int off = 32; off; off >>= 1){
    s  += __shfl_down(s, off);
    s2 += __shfl_down(s2, off);
  }
  int wid = threadIdx.x >> 6, lane = threadIdx.x & 63;
  int nw = blockDim.x >> 6;
  if (lane == 0){ ls[wid] = s; ls2[wid] = s2; }
  __syncthreads();
  if (threadIdx.x == 0){
    float a = ls[0], b = ls2[0];
    for (int i = 1; i < nw; i++){ a += ls[i]; b += ls2[i]; }
    ls[0] = a; ls2[0] = b;
  }
  __syncthreads();
  s = ls[0]; s2 = ls2[0];
}

// out[idx] = x[idx] + pe(l, c)   where pe[l][c] = c<half ? sin(l*rate[c]) : cos(l*rate[c-half])
__global__ void pe_add_kernel(const float* __restrict__ x, float* __restrict__ out,
                              int C, int half, int L, int total){
  const float l2r = 13.28771237954945f; // log2(10000)
  for (int idx = blockIdx.x * blockDim.x + threadIdx.x; idx < total;
       idx += gridDim.x * blockDim.x){
    int l = idx % L;
    int c = (idx / L) % C;
    int d = (c < half) ? c : c - half;
    float rate = exp2f(-l2r * (float)d / (float)half);
    float ang  = (float)l * rate;
    float pe   = (c < half) ? sinf(ang) : cosf(ang);
    out[idx] = x[idx] + pe;
  }
}

// ReflectionPad2d(1) + 3x3 conv (cross-correlation, OIHW), optional nearest-2x
// upsample of the input (applied BEFORE padding), optional stride.
// Virtual input size = (up?2*Hin:Hin) x (up?2*Win:Win); output Hout x Wout.
__global__ void conv_refl_kernel(const float* __restrict__ in, const float* __restrict__ w,
                                 float* __restrict__ out,
                                 int Cin, int Hin, int Win,
                                 int Cout, int Hout, int Wout,
                                 int stride, int upsample){
  int b  = blockIdx.z;
  int co = blockIdx.y;
  int sp = blockIdx.x * blockDim.x + threadIdx.x;
  if (sp >= Hout * Wout) return;
  int oh = sp / Wout, ow = sp % Wout;
  int VH = upsample ? 2 * Hin : Hin;
  int VW = upsample ? 2 * Win : Win;

  int ihs[3], iws[3];
  #pragma unroll
  for (int k = 0; k < 3; k++){
    int ih = oh * stride - 1 + k;
    ih = (ih < 0) ? -ih : ((ih >= VH) ? 2 * VH - 2 - ih : ih);
    ihs[k] = upsample ? (ih >> 1) : ih;
    int iw = ow * stride - 1 + k;
    iw = (iw < 0) ? -iw : ((iw >= VW) ? 2 * VW - 2 - iw : iw);
    iws[k] = upsample ? (iw >> 1) : iw;
  }

  const float* inb  = in + (long)b * Cin * Hin * Win;
  const float* wrow = w + (long)co * Cin * 9;
  float a0 = 0.f, a1 = 0.f, a2 = 0.f;
  for (int ci = 0; ci < Cin; ci++){
    const float* p  = inb + (long)ci * Hin * Win;
    const float* wp = wrow + ci * 9;
    const float* r0 = p + ihs[0] * Win;
    const float* r1 = p + ihs[1] * Win;
    const float* r2 = p + ihs[2] * Win;
    a0 += r0[iws[0]] * wp[0] + r0[iws[1]] * wp[1] + r0[iws[2]] * wp[2];
    a1 += r1[iws[0]] * wp[3] + r1[iws[1]] * wp[4] + r1[iws[2]] * wp[5];
    a2 += r2[iws[0]] * wp[6] + r2[iws[1]] * wp[7] + r2[iws[2]] * wp[8];
  }
  out[((long)(b * Cout + co)) * Hout * Wout + sp] = a0 + a1 + a2;
}

// In-place InstanceNorm (biased var, eps=1e-5) + SiLU. One block per (b,c).
__global__ void in_silu_kernel(float* __restrict__ x, int HW){
  long bc = blockIdx.x;
  float* p = x + bc * HW;
  float s = 0.f, s2 = 0.f;
  for (int i = threadIdx.x; i < HW; i += blockDim.x){
    float v = p[i]; s += v; s2 += v * v;
  }
  block_reduce2(s, s2);
  float mean = s / (float)HW;
  float var  = s2 / (float)HW - mean * mean;
  float rstd = rsqrtf(var + EPS);
  for (int i = threadIdx.x; i < HW; i += blockDim.x){
    float v = (p[i] - mean) * rstd;
    p[i] = v * sigmoidf_(v);
  }
}

// Self-attention (q=k), 4 heads, d=32. q,v layout: [B,128,N] channel-major.
// One wave per (b, h, query). Two passes over keys (max, then exp/accum).
__global__ void attn_kernel(const float* __restrict__ q, const float* __restrict__ v,
                            float* __restrict__ o, int N){
  int gwid = (blockIdx.x * blockDim.x + threadIdx.x) >> 6;
  int lane = threadIdx.x & 63;
  int ql = gwid & (N - 1);
  int bh = gwid / N;            // 0..7
  int h = bh & 3, b = bh >> 2;
  const float* qb = q + ((long)b * 128 + h * 32) * N;
  const float* vb = v + ((long)b * 128 + h * 32) * N;

  float qv[32];
  #pragma unroll
  for (int c = 0; c < 32; c++) qv[c] = qb[(long)c * N + ql] * 0.17677669529663687f; // 1/sqrt(32)

  // pass 1: global max of scores
  float m = -1e30f;
  for (int j = lane; j < N; j += 64){
    float sd = 0.f;
    #pragma unroll
    for (int c = 0; c < 32; c++) sd += qv[c] * qb[(long)c * N + j];
    m = fmaxf(m, sd);
  }
  #pragma unroll
  for (int off = 32; off; off >>= 1) m = fmaxf(m, __shfl_xor(m, off));

  // pass 2: exp & accumulate
  float l = 0.f;
  float acc[32];
  #pragma unroll
  for (int c = 0; c < 32; c++) acc[c] = 0.f;
  for (int j = lane; j < N; j += 64){
    float sd = 0.f;
    #pragma unroll
    for (int c = 0; c < 32; c++) sd += qv[c] * qb[(long)c * N + j];
    float p = __expf(sd - m);
    l += p;
    #pragma unroll
    for (int c = 0; c < 32; c++) acc[c] += p * vb[(long)c * N + j];
  }
  #pragma unroll
  for (int off = 32; off; off >>= 1){
    l += __shfl_xor(l, off);
    #pragma unroll
    for (int c = 0; c < 32; c++) acc[c] += __shfl_xor(acc[c], off);
  }
  if (lane == 0){
    float inv = 1.f / l;
    #pragma unroll
    for (int c = 0; c < 32; c++)
      o[((long)b * 128 + h * 32 + c) * N + ql] = acc[c] * inv;
  }
}

// Per-(b,c) sum / sumsq over HW
__global__ void stats_kernel(const float* __restrict__ x, float* __restrict__ sums,
                             float* __restrict__ sumsqs, int HW){
  long bc = blockIdx.x;
  const float* p = x + bc * HW;
  float s = 0.f, s2 = 0.f;
  for (int i = threadIdx.x; i < HW; i += blockDim.x){
    float v = p[i]; s += v; s2 += v * v;
  }
  block_reduce2(s, s2);
  if (threadIdx.x == 0){ sums[bc] = s; sumsqs[bc] = s2; }
}

// Per-b reduction of channel sums -> layer sums
__global__ void layer_reduce_kernel(const float* __restrict__ sums, const float* __restrict__ sumsqs,
                                    float* __restrict__ lsum, float* __restrict__ lsumsq, int C){
  int b = blockIdx.x;
  float s = 0.f, s2 = 0.f;
  for (int c = threadIdx.x; c < C; c += blockDim.x){
    s += sums[b * C + c]; s2 += sumsqs[b * C + c];
  }
  block_reduce2(s, s2);
  if (threadIdx.x == 0){ lsum[b] = s; lsumsq[b] = s2; }
}

// ILN (unbiased vars) + affine + activation; mode 0: sigmoid(x)*gate, mode 1: silu(x).
// Writes into out channel slot (co_off + c) of a Cout_total-channel tensor.
__global__ void iln_finalize_kernel(const float* __restrict__ x,
                                    const float* __restrict__ sums, const float* __restrict__ sumsqs,
                                    const float* __restrict__ lsum, const float* __restrict__ lsumsq,
                                    const float* __restrict__ rho, const float* __restrict__ gamma,
                                    const float* __restrict__ beta,
                                    const float* __restrict__ gate,
                                    float* __restrict__ out,
                                    int HW, int C, int co_off, int Cout_total, int mode){
  int bc = blockIdx.y;
  int b = bc / C, c = bc % C;
  float n = (float)HW;
  float im = sums[bc] / n;
  float iv = (sumsqs[bc] / n - im * im) * (n / (n - 1.f));
  float ir = rsqrtf(iv + EPS);
  float n2 = n * (float)C;
  float lm = lsum[b] / n2;
  float lv = (lsumsq[b] / n2 - lm * lm) * (n2 / (n2 - 1.f));
  float lr = rsqrtf(lv + EPS);
  float r = rho[c], g = gamma[c], bb = beta[c];

  const float* xp = x + (long)bc * HW;
  const float* gp = gate ? gate + (long)bc * HW : nullptr;
  float* op = out + ((long)(b * Cout_total + co_off + c)) * HW;
  for (int i = blockIdx.x * blockDim.x + threadIdx.x; i < HW; i += gridDim.x * blockDim.x){
    float xv = xp[i];
    float t = r * (xv - im) * ir + (1.f - r) * (xv - lm) * lr;
    t = t * g + bb;
    float sg = sigmoidf_(t);
    op[i] = mode ? t * sg : sg * gp[i];
  }
}

extern "C" void kernel_launch(void* const* d_in, const int* in_sizes, int n_in,
                              void* d_out, int out_size, void* d_ws, size_t ws_size,
                              hipStream_t stream){
  const float* y        = (const float*)d_in[0];
  const float* s        = (const float*)d_in[1];
  const float* w_blue_s = (const float*)d_in[2];
  const float* w_blue_y = (const float*)d_in[3];
  const float* w_purple = (const float*)d_in[4];
  const float* rho_p    = (const float*)d_in[5];
  const float* gamma_p  = (const float*)d_in[6];
  const float* beta_p   = (const float*)d_in[7];
  const float* w_green  = (const float*)d_in[8];
  const float* rho_g    = (const float*)d_in[9];
  const float* gamma_g  = (const float*)d_in[10];
  const float* beta_g   = (const float*)d_in[11];
  float* out = (float*)d_out;
  float* ws  = (float*)d_ws;

  const int B = 2, SC = 128, N = 4096, NS = 16384;

  // workspace layout (floats); purple_raw reuses s_pe (dead after blue_s conv)
  float* s_pe       = ws;                    // 4,194,304
  float* y_pe       = s_pe + 4194304;        // 2,097,152
  float* qbuf       = y_pe + 2097152;        // 1,048,576
  float* vbuf       = qbuf + 1048576;        // 1,048,576
  float* mhabuf     = vbuf + 1048576;        // 1,048,576
  float* green_raw  = mhabuf + 1048576;      // 4,194,304
  float* stats      = green_raw + 4194304;   // 2048
  float* purple_raw = s_pe;
  float* sumsG = stats,        *sumsqG = stats + 256;
  float* sumsP = stats + 512,  *sumsqP = stats + 768;
  float* lsumG = stats + 1024, *lsumsqG = stats + 1026;
  float* lsumP = stats + 1028, *lsumsqP = stats + 1030;

  dim3 blk(256);

  // 1) positional encodings
  pe_add_kernel<<<dim3(2048), blk, 0, stream>>>(y, y_pe, 256, 128, N, 2 * 256 * N);
  pe_add_kernel<<<dim3(2048), blk, 0, stream>>>(s, s_pe, 128, 64, NS, 2 * 128 * NS);

  // 2) blue convs  (q: 256->128 on 64x64 s1;  v: 128->128 on 128x128 s2)
  conv_refl_kernel<<<dim3(16, 128, B), blk, 0, stream>>>(y_pe, w_blue_y, qbuf,
      256, 64, 64, 128, 64, 64, 1, 0);
  conv_refl_kernel<<<dim3(16, 128, B), blk, 0, stream>>>(s_pe, w_blue_s, vbuf,
      128, 128, 128, 128, 64, 64, 2, 0);

  // 3) instance norm + SiLU (in place)
  in_silu_kernel<<<dim3(B * SC), blk, 0, stream>>>(qbuf, N);
  in_silu_kernel<<<dim3(B * SC), blk, 0, stream>>>(vbuf, N);

  // 4) attention (q=k), 4 heads, d=32  -> mhabuf [B,128,N]
  attn_kernel<<<dim3(B * 4 * N / 4), blk, 0, stream>>>(qbuf, vbuf, mhabuf, N);

  // 5) green conv: upsample2(y) -> 128x128, 256->128
  conv_refl_kernel<<<dim3(64, 128, B), blk, 0, stream>>>(y, w_green, green_raw,
      256, 64, 64, 128, 128, 128, 1, 1);

  // 6) purple conv: upsample2(mha2d) -> 128x128, 128->128
  conv_refl_kernel<<<dim3(64, 128, B), blk, 0, stream>>>(mhabuf, w_purple, purple_raw,
      128, 64, 64, 128, 128, 128, 1, 1);

  // 7) ILN stats
  stats_kernel<<<dim3(B * SC), blk, 0, stream>>>(green_raw, sumsG, sumsqG, NS);
  stats_kernel<<<dim3(B * SC), blk, 0, stream>>>(purple_raw, sumsP, sumsqP, NS);
  layer_reduce_kernel<<<dim3(B), dim3(64), 0, stream>>>(sumsG, sumsqG, lsumG, lsumsqG, SC);
  layer_reduce_kernel<<<dim3(B), dim3(64), 0, stream>>>(sumsP, sumsqP, lsumP, lsumsqP, SC);

  // 8) finalize: z -> out[:, :128], up_y -> out[:, 128:]
  iln_finalize_kernel<<<dim3(64, B * SC), blk, 0, stream>>>(purple_raw, sumsP, sumsqP,
      lsumP, lsumsqP, rho_p, gamma_p, beta_p, s, out, NS, SC, 0, 256, 0);
  iln_finalize_kernel<<<dim3(64, B * SC), blk, 0, stream>>>(green_raw, sumsG, sumsqG,
      lsumG, lsumsqG, rho_g, gamma_g, beta_g, nullptr, out, NS, SC, 128, 256, 1);
}

// Round 2
// 2531.392 us; speedup vs baseline: 1.9629x; 1.9629x over previous
//
#include <hip/hip_runtime.h>
#include <math.h>

#define EPS 1e-5f

typedef __attribute__((ext_vector_type(8))) short bf16x8;
typedef __attribute__((ext_vector_type(4))) float f32x4;

__device__ __forceinline__ float sigmoidf_(float x){ return 1.f/(1.f+__expf(-x)); }

__device__ __forceinline__ unsigned short f2bf(float f){
  union { float f; unsigned int u; } c; c.f = f;
  unsigned int u = c.u + 0x7FFF + ((c.u >> 16) & 1);   // RNE
  return (unsigned short)(u >> 16);
}

// block-wide reduction of two accumulators; blockDim.x must be a multiple of 64
__device__ __forceinline__ void block_reduce2(float& s, float& s2){
  __shared__ float ls[16], ls2[16];
  #pragma unroll
  for (int off = 32; off; off >>= 1){
    s  += __shfl_down(s, off);
    s2 += __shfl_down(s2, off);
  }
  int wid = threadIdx.x >> 6, lane = threadIdx.x & 63;
  int nw = blockDim.x >> 6;
  if (lane == 0){ ls[wid] = s; ls2[wid] = s2; }
  __syncthreads();
  if (threadIdx.x == 0){
    float a = ls[0], b = ls2[0];
    for (int i = 1; i < nw; i++){ a += ls[i]; b += ls2[i]; }
    ls[0] = a; ls2[0] = b;
  }
  __syncthreads();
  s = ls[0]; s2 = ls2[0];
}

__global__ void pe_add_kernel(const float* __restrict__ x, float* __restrict__ out,
                              int C, int half, int L, int total){
  const float l2r = 13.28771237954945f; // log2(10000)
  for (int idx = blockIdx.x * blockDim.x + threadIdx.x; idx < total;
       idx += gridDim.x * blockDim.x){
    int l = idx % L;
    int c = (idx / L) % C;
    int d = (c < half) ? c : c - half;
    float rate = exp2f(-l2r * (float)d / (float)half);
    float ang  = (float)l * rate;
    float pe   = (c < half) ? sinf(ang) : cosf(ang);
    out[idx] = x[idx] + pe;
  }
}

// ReflectionPad2d(1) + 3x3 conv, optional nearest-2x upsample, optional stride.
__global__ void conv_refl_kernel(const float* __restrict__ in, const float* __restrict__ w,
                                 float* __restrict__ out,
                                 int Cin, int Hin, int Win,
                                 int Cout, int Hout, int Wout,
                                 int stride, int upsample){
  int b  = blockIdx.z;
  int co = blockIdx.y;
  int sp = blockIdx.x * blockDim.x + threadIdx.x;
  if (sp >= Hout * Wout) return;
  int oh = sp / Wout, ow = sp % Wout;
  int VH = upsample ? 2 * Hin : Hin;
  int VW = upsample ? 2 * Win : Win;

  int ihs[3], iws[3];
  #pragma unroll
  for (int k = 0; k < 3; k++){
    int ih = oh * stride - 1 + k;
    ih = (ih < 0) ? -ih : ((ih >= VH) ? 2 * VH - 2 - ih : ih);
    ihs[k] = upsample ? (ih >> 1) : ih;
    int iw = ow * stride - 1 + k;
    iw = (iw < 0) ? -iw : ((iw >= VW) ? 2 * VW - 2 - iw : iw);
    iws[k] = upsample ? (iw >> 1) : iw;
  }

  const float* inb  = in + (long)b * Cin * Hin * Win;
  const float* wrow = w + (long)co * Cin * 9;
  float a0 = 0.f, a1 = 0.f, a2 = 0.f;
  for (int ci = 0; ci < Cin; ci++){
    const float* p  = inb + (long)ci * Hin * Win;
    const float* wp = wrow + ci * 9;
    const float* r0 = p + ihs[0] * Win;
    const float* r1 = p + ihs[1] * Win;
    const float* r2 = p + ihs[2] * Win;
    a0 += r0[iws[0]] * wp[0] + r0[iws[1]] * wp[1] + r0[iws[2]] * wp[2];
    a1 += r1[iws[0]] * wp[3] + r1[iws[1]] * wp[4] + r1[iws[2]] * wp[5];
    a2 += r2[iws[0]] * wp[6] + r2[iws[1]] * wp[7] + r2[iws[2]] * wp[8];
  }
  out[((long)(b * Cout + co)) * Hout * Wout + sp] = a0 + a1 + a2;
}

// InstanceNorm+SiLU, output bf16 TRANSPOSED for attention Q/K: outT[bh][pos][32]
__global__ void in_silu_qk_kernel(const float* __restrict__ x, unsigned short* __restrict__ outT,
                                  int HW){
  int bc = blockIdx.x;                 // b*128 + cg
  const float* p = x + (long)bc * HW;
  float s = 0.f, s2 = 0.f;
  for (int i = threadIdx.x; i < HW; i += blockDim.x){
    float v = p[i]; s += v; s2 += v * v;
  }
  block_reduce2(s, s2);
  float mean = s / (float)HW;
  float var  = s2 / (float)HW - mean * mean;
  float rstd = rsqrtf(var + EPS);
  int b = bc >> 7, cg = bc & 127, h = cg >> 5, d = cg & 31;
  unsigned short* op = outT + ((long)(b * 4 + h) * HW) * 32 + d;
  for (int i = threadIdx.x; i < HW; i += blockDim.x){
    float v = (p[i] - mean) * rstd;
    v = v * sigmoidf_(v);
    op[(long)i * 32] = f2bf(v);
  }
}

// InstanceNorm+SiLU, output bf16 in channel-major layout (= V^T per head slice)
__global__ void in_silu_v_kernel(const float* __restrict__ x, unsigned short* __restrict__ out,
                                 int HW){
  int bc = blockIdx.x;
  const float* p = x + (long)bc * HW;
  float s = 0.f, s2 = 0.f;
  for (int i = threadIdx.x; i < HW; i += blockDim.x){
    float v = p[i]; s += v; s2 += v * v;
  }
  block_reduce2(s, s2);
  float mean = s / (float)HW;
  float var  = s2 / (float)HW - mean * mean;
  float rstd = rsqrtf(var + EPS);
  unsigned short* op = out + (long)bc * HW;
  for (int i = threadIdx.x; i < HW; i += blockDim.x){
    float v = (p[i] - mean) * rstd;
    op[i] = f2bf(v * sigmoidf_(v));
  }
}

// MFMA flash attention. q=k: qk [bh][N][32] bf16; v: [b*128+c][N] bf16 (V^T per head).
// Output o fp32 [b][128][N]. Block: 4 waves x 16 queries = 64 queries; 64-key tiles in LDS.
__global__ __launch_bounds__(256) void flash_attn_kernel(
    const unsigned short* __restrict__ qk,
    const unsigned short* __restrict__ vt,
    float* __restrict__ o, int N){
  __shared__ __align__(16) unsigned short Klds[64 * 40];  // [key][d], stride 40
  __shared__ __align__(16) unsigned short Vlds[32 * 72];  // [d][key], stride 72
  const float SCALE = 0.17677669529663687f;               // 1/sqrt(32)

  int bh = blockIdx.y;
  int b = bh >> 2, h = bh & 3;
  int tid = threadIdx.x;
  int wid = tid >> 6, lane = tid & 63;
  int lg = lane >> 4, lr = lane & 15;
  const unsigned short* qbase = qk + (long)bh * N * 32;
  const unsigned short* vbase = vt + (long)(b * 128 + h * 32) * N;

  // Q fragment: row = query (lr), k-elems d = lg*4+j (j<4) and 16+lg*4+(j-4)
  int q0w = blockIdx.x * 64 + wid * 16;
  bf16x8 qf;
  {
    const unsigned short* qp = qbase + (long)(q0w + lr) * 32 + lg * 4;
    ushort4 a = *(const ushort4*)qp;
    ushort4 c = *(const ushort4*)(qp + 16);
    qf[0]=a.x; qf[1]=a.y; qf[2]=a.z; qf[3]=a.w;
    qf[4]=c.x; qf[5]=c.y; qf[6]=c.z; qf[7]=c.w;
  }

  float m_run = -1e30f, l_run = 0.f;
  f32x4 acc0 = {0.f,0.f,0.f,0.f}, acc1 = {0.f,0.f,0.f,0.f};

  for (int k0 = 0; k0 < N; k0 += 64){
    __syncthreads();
    {
      int key = tid >> 2, q4 = tid & 3;      // K tile: 64 keys x 32 d
      *(uint4*)(&Klds[key * 40 + q4 * 8]) =
          *(const uint4*)(qbase + (long)(k0 + key) * 32 + q4 * 8);
      int d = tid >> 3, oct = tid & 7;       // V tile: 32 d x 64 keys
      *(uint4*)(&Vlds[d * 72 + oct * 8]) =
          *(const uint4*)(vbase + (long)d * N + k0 + oct * 8);
    }
    __syncthreads();

    // S^T = K_tile x Q^T : 4 blocks of 16 keys
    f32x4 st[4];
    #pragma unroll
    for (int kb = 0; kb < 4; kb++){
      const unsigned short* kp = &Klds[(kb * 16 + lr) * 40 + lg * 4];
      ushort4 x = *(const ushort4*)kp;
      ushort4 y = *(const ushort4*)(kp + 16);
      bf16x8 kf;
      kf[0]=x.x; kf[1]=x.y; kf[2]=x.z; kf[3]=x.w;
      kf[4]=y.x; kf[5]=y.y; kf[6]=y.z; kf[7]=y.w;
      st[kb] = __builtin_amdgcn_mfma_f32_16x16x32_bf16(kf, qf,
                  (f32x4){0.f,0.f,0.f,0.f}, 0, 0, 0);
    }

    // online softmax; lane holds 16 keys for query lr
    float mt = -1e30f;
    #pragma unroll
    for (int kb = 0; kb < 4; kb++)
      #pragma unroll
      for (int r = 0; r < 4; r++){
        st[kb][r] *= SCALE;
        mt = fmaxf(mt, st[kb][r]);
      }
    mt = fmaxf(mt, __shfl_xor(mt, 16));
    mt = fmaxf(mt, __shfl_xor(mt, 32));
    float m_new  = fmaxf(m_run, mt);
    float fscale = __expf(m_run - m_new);
    float lt = 0.f;
    unsigned short pu[16];
    #pragma unroll
    for (int kb = 0; kb < 4; kb++)
      #pragma unroll
      for (int r = 0; r < 4; r++){
        float p = __expf(st[kb][r] - m_new);
        lt += p;
        pu[kb * 4 + r] = f2bf(p);
      }
    lt += __shfl_xor(lt, 16);
    lt += __shfl_xor(lt, 32);
    l_run = l_run * fscale + lt;
    m_run = m_new;

    // rescale O (O-space: lane holds queries lg*4+r) by per-query factor
    float fr[4];
    #pragma unroll
    for (int r = 0; r < 4; r++) fr[r] = __shfl(fscale, lg * 4 + r);
    #pragma unroll
    for (int r = 0; r < 4; r++){ acc0[r] *= fr[r]; acc1[r] *= fr[r]; }

    // PV: two K=32 MFMAs per d-block
    #pragma unroll
    for (int m = 0; m < 2; m++){
      bf16x8 pf;
      #pragma unroll
      for (int j = 0; j < 4; j++){
        pf[j]     = (short)pu[(2 * m) * 4 + j];
        pf[j + 4] = (short)pu[(2 * m + 1) * 4 + j];
      }
      const unsigned short* vp0 = &Vlds[lr * 72 + m * 32 + lg * 4];
      const unsigned short* vp1 = &Vlds[(16 + lr) * 72 + m * 32 + lg * 4];
      ushort4 x0 = *(const ushort4*)vp0, y0 = *(const ushort4*)(vp0 + 16);
      ushort4 x1 = *(const ushort4*)vp1, y1 = *(const ushort4*)(vp1 + 16);
      bf16x8 vf0, vf1;
      vf0[0]=x0.x; vf0[1]=x0.y; vf0[2]=x0.z; vf0[3]=x0.w;
      vf0[4]=y0.x; vf0[5]=y0.y; vf0[6]=y0.z; vf0[7]=y0.w;
      vf1[0]=x1.x; vf1[1]=x1.y; vf1[2]=x1.z; vf1[3]=x1.w;
      vf1[4]=y1.x; vf1[5]=y1.y; vf1[6]=y1.z; vf1[7]=y1.w;
      acc0 = __builtin_amdgcn_mfma_f32_16x16x32_bf16(pf, vf0, acc0, 0, 0, 0);
      acc1 = __builtin_amdgcn_mfma_f32_16x16x32_bf16(pf, vf1, acc1, 0, 0, 0);
    }
  }

  float inv = 1.f / l_run;
  float ir[4];
  #pragma unroll
  for (int r = 0; r < 4; r++) ir[r] = __shfl(inv, lg * 4 + r);
  float* ob = o + (long)(b * 128 + h * 32) * N;
  #pragma unroll
  for (int r = 0; r < 4; r++){
    int q = q0w + lg * 4 + r;
    ob[(long)lr * N + q]        = acc0[r] * ir[r];
    ob[(long)(16 + lr) * N + q] = acc1[r] * ir[r];
  }
}

// Per-(b,c) sum / sumsq over HW
__global__ void stats_kernel(const float* __restrict__ x, float* __restrict__ sums,
                             float* __restrict__ sumsqs, int HW){
  long bc = blockIdx.x;
  const float* p = x + bc * HW;
  float s = 0.f, s2 = 0.f;
  for (int i = threadIdx.x; i < HW; i += blockDim.x){
    float v = p[i]; s += v; s2 += v * v;
  }
  block_reduce2(s, s2);
  if (threadIdx.x == 0){ sums[bc] = s; sumsqs[bc] = s2; }
}

__global__ void layer_reduce_kernel(const float* __restrict__ sums, const float* __restrict__ sumsqs,
                                    float* __restrict__ lsum, float* __restrict__ lsumsq, int C){
  int b = blockIdx.x;
  float s = 0.f, s2 = 0.f;
  for (int c = threadIdx.x; c < C; c += blockDim.x){
    s += sums[b * C + c]; s2 += sumsqs[b * C + c];
  }
  block_reduce2(s, s2);
  if (threadIdx.x == 0){ lsum[b] = s; lsumsq[b] = s2; }
}

__global__ void iln_finalize_kernel(const float* __restrict__ x,
                                    const float* __restrict__ sums, const float* __restrict__ sumsqs,
                                    const float* __restrict__ lsum, const float* __restrict__ lsumsq,
                                    const float* __restrict__ rho, const float* __restrict__ gamma,
                                    const float* __restrict__ beta,
                                    const float* __restrict__ gate,
                                    float* __restrict__ out,
                                    int HW, int C, int co_off, int Cout_total, int mode){
  int bc = blockIdx.y;
  int b = bc / C, c = bc % C;
  float n = (float)HW;
  float im = sums[bc] / n;
  float iv = (sumsqs[bc] / n - im * im) * (n / (n - 1.f));
  float ir = rsqrtf(iv + EPS);
  float n2 = n * (float)C;
  float lm = lsum[b] / n2;
  float lv = (lsumsq[b] / n2 - lm * lm) * (n2 / (n2 - 1.f));
  float lr = rsqrtf(lv + EPS);
  float r = rho[c], g = gamma[c], bb = beta[c];

  const float* xp = x + (long)bc * HW;
  const float* gp = gate ? gate + (long)bc * HW : nullptr;
  float* op = out + ((long)(b * Cout_total + co_off + c)) * HW;
  for (int i = blockIdx.x * blockDim.x + threadIdx.x; i < HW; i += gridDim.x * blockDim.x){
    float xv = xp[i];
    float t = r * (xv - im) * ir + (1.f - r) * (xv - lm) * lr;
    t = t * g + bb;
    float sg = sigmoidf_(t);
    op[i] = mode ? t * sg : sg * gp[i];
  }
}

extern "C" void kernel_launch(void* const* d_in, const int* in_sizes, int n_in,
                              void* d_out, int out_size, void* d_ws, size_t ws_size,
                              hipStream_t stream){
  const float* y        = (const float*)d_in[0];
  const float* s        = (const float*)d_in[1];
  const float* w_blue_s = (const float*)d_in[2];
  const float* w_blue_y = (const float*)d_in[3];
  const float* w_purple = (const float*)d_in[4];
  const float* rho_p    = (const float*)d_in[5];
  const float* gamma_p  = (const float*)d_in[6];
  const float* beta_p   = (const float*)d_in[7];
  const float* w_green  = (const float*)d_in[8];
  const float* rho_g    = (const float*)d_in[9];
  const float* gamma_g  = (const float*)d_in[10];
  const float* beta_g   = (const float*)d_in[11];
  float* out = (float*)d_out;
  float* ws  = (float*)d_ws;

  const int B = 2, SC = 128, N = 4096, NS = 16384;

  float* s_pe       = ws;                    // 4,194,304 f
  float* y_pe       = s_pe + 4194304;        // 2,097,152 f
  float* qbuf       = y_pe + 2097152;        // 1,048,576 f
  float* vbuf       = qbuf + 1048576;        // 1,048,576 f
  float* mhabuf     = vbuf + 1048576;        // 1,048,576 f
  float* green_raw  = mhabuf + 1048576;      // 4,194,304 f
  float* stats      = green_raw + 4194304;   // 2048 f
  float* purple_raw = s_pe;                  // overlays s_pe (dead after blue_s)
  // qk_bf / v_bf overlay green_raw (green conv runs after attention)
  unsigned short* qk_bf = (unsigned short*)green_raw;   // 1,048,576 ushort
  unsigned short* v_bf  = qk_bf + 1048576;              // 1,048,576 ushort
  float* sumsG = stats,        *sumsqG = stats + 256;
  float* sumsP = stats + 512,  *sumsqP = stats + 768;
  float* lsumG = stats + 1024, *lsumsqG = stats + 1026;
  float* lsumP = stats + 1028, *lsumsqP = stats + 1030;

  dim3 blk(256);

  // 1) positional encodings
  pe_add_kernel<<<dim3(2048), blk, 0, stream>>>(y, y_pe, 256, 128, N, 2 * 256 * N);
  pe_add_kernel<<<dim3(2048), blk, 0, stream>>>(s, s_pe, 128, 64, NS, 2 * 128 * NS);

  // 2) blue convs
  conv_refl_kernel<<<dim3(16, 128, B), blk, 0, stream>>>(y_pe, w_blue_y, qbuf,
      256, 64, 64, 128, 64, 64, 1, 0);
  conv_refl_kernel<<<dim3(16, 128, B), blk, 0, stream>>>(s_pe, w_blue_s, vbuf,
      128, 128, 128, 128, 64, 64, 2, 0);

  // 3) instance norm + SiLU -> bf16 attention layouts
  in_silu_qk_kernel<<<dim3(B * SC), blk, 0, stream>>>(qbuf, qk_bf, N);
  in_silu_v_kernel<<<dim3(B * SC), blk, 0, stream>>>(vbuf, v_bf, N);

  // 4) MFMA flash attention -> mhabuf fp32 [b][128][N]
  flash_attn_kernel<<<dim3(N / 64, B * 4), blk, 0, stream>>>(qk_bf, v_bf, mhabuf, N);

  // 5) green conv: upsample2(y) -> 128x128, 256->128  (overwrites qk_bf/v_bf region)
  conv_refl_kernel<<<dim3(64, 128, B), blk, 0, stream>>>(y, w_green, green_raw,
      256, 64, 64, 128, 128, 128, 1, 1);

  // 6) purple conv: upsample2(mha2d) -> 128x128, 128->128
  conv_refl_kernel<<<dim3(64, 128, B), blk, 0, stream>>>(mhabuf, w_purple, purple_raw,
      128, 64, 64, 128, 128, 128, 1, 1);

  // 7) ILN stats
  stats_kernel<<<dim3(B * SC), blk, 0, stream>>>(green_raw, sumsG, sumsqG, NS);
  stats_kernel<<<dim3(B * SC), blk, 0, stream>>>(purple_raw, sumsP, sumsqP, NS);
  layer_reduce_kernel<<<dim3(B), dim3(64), 0, stream>>>(sumsG, sumsqG, lsumG, lsumsqG, SC);
  layer_reduce_kernel<<<dim3(B), dim3(64), 0, stream>>>(sumsP, sumsqP, lsumP, lsumsqP, SC);

  // 8) finalize
  iln_finalize_kernel<<<dim3(64, B * SC), blk, 0, stream>>>(purple_raw, sumsP, sumsqP,
      lsumP, lsumsqP, rho_p, gamma_p, beta_p, s, out, NS, SC, 0, 256, 0);
  iln_finalize_kernel<<<dim3(64, B * SC), blk, 0, stream>>>(green_raw, sumsG, sumsqG,
      lsumG, lsumsqG, rho_g, gamma_g, beta_g, nullptr, out, NS, SC, 128, 256, 1);
}

// Round 4
// 412.013 us; speedup vs baseline: 12.0600x; 6.1440x over previous
//
#include <hip/hip_runtime.h>
#include <math.h>

#define EPS 1e-5f

typedef __attribute__((ext_vector_type(8))) _Float16 f16x8;
typedef __attribute__((ext_vector_type(4))) float f32x4;

union H8u { ushort4 u[2]; f16x8 h; };
union H8e { unsigned short us[8]; f16x8 h; };

__device__ __forceinline__ float sigmoidf_(float x){ return 1.f/(1.f+__expf(-x)); }

__device__ __forceinline__ unsigned short f2h(float f){
  union { _Float16 h; unsigned short u; } c;
  c.h = (_Float16)f;            // v_cvt_f16_f32, RNE
  return c.u;
}

// block-wide reduction of two accumulators; blockDim.x must be a multiple of 64
__device__ __forceinline__ void block_reduce2(float& s, float& s2){
  __shared__ float ls[16], ls2[16];
  #pragma unroll
  for (int off = 32; off; off >>= 1){
    s  += __shfl_down(s, off);
    s2 += __shfl_down(s2, off);
  }
  int wid = threadIdx.x >> 6, lane = threadIdx.x & 63;
  int nw = blockDim.x >> 6;
  if (lane == 0){ ls[wid] = s; ls2[wid] = s2; }
  __syncthreads();
  if (threadIdx.x == 0){
    float a = ls[0], b = ls2[0];
    for (int i = 1; i < nw; i++){ a += ls[i]; b += ls2[i]; }
    ls[0] = a; ls2[0] = b;
  }
  __syncthreads();
  s = ls[0]; s2 = ls2[0];
}

// Fused (optional PE-add) + fp16 cast + transpose: x [B][C][L] fp32 -> xt [B][L][C] fp16
// grid: (L/64, C/64, B), block 256
__global__ __launch_bounds__(256) void pe_t_kernel(
    const float* __restrict__ x, unsigned short* __restrict__ xt,
    int C, int L, int half, int addpe){
  __shared__ unsigned short tile[64][72];
  int b = blockIdx.z;
  int c0 = blockIdx.y * 64, l0 = blockIdx.x * 64;
  int tid = threadIdx.x;
  const float l2r = 13.28771237954945f; // log2(10000)
  #pragma unroll
  for (int i = 0; i < 4; i++){
    int id = tid + i * 256;              // 0..1023
    int c = id >> 4, ch = (id & 15) * 4; // 64 c-rows x 16 float4 chunks (L offset)
    int cg = c0 + c;
    float4 v = *(const float4*)&x[((long)b * C + cg) * L + l0 + ch];
    float pe0 = 0.f, pe1 = 0.f, pe2 = 0.f, pe3 = 0.f;
    if (addpe){
      int d = cg < half ? cg : cg - half;
      float rate = exp2f(-l2r * (float)d / (float)half);
      float a0 = (float)(l0 + ch) * rate;
      if (cg < half){ pe0 = sinf(a0); pe1 = sinf(a0 + rate); pe2 = sinf(a0 + 2.f*rate); pe3 = sinf(a0 + 3.f*rate); }
      else          { pe0 = cosf(a0); pe1 = cosf(a0 + rate); pe2 = cosf(a0 + 2.f*rate); pe3 = cosf(a0 + 3.f*rate); }
    }
    ushort4 o;
    o.x = f2h(v.x + pe0); o.y = f2h(v.y + pe1);
    o.z = f2h(v.z + pe2); o.w = f2h(v.w + pe3);
    *(ushort4*)&tile[c][ch] = o;
  }
  __syncthreads();
  #pragma unroll
  for (int i = 0; i < 2; i++){
    int id = tid + i * 256;              // 0..511
    int l = id >> 3, ch = (id & 7) * 8;  // 64 l-rows x 8 chunks (C offset)
    ushort4 a, bq;
    a.x = tile[ch+0][l]; a.y = tile[ch+1][l]; a.z = tile[ch+2][l]; a.w = tile[ch+3][l];
    bq.x = tile[ch+4][l]; bq.y = tile[ch+5][l]; bq.z = tile[ch+6][l]; bq.w = tile[ch+7][l];
    unsigned short* op = &xt[((long)b * L + l0 + l) * C + c0 + ch];
    *(ushort4*)op = a;
    *(ushort4*)(op + 4) = bq;
  }
}

// Weight repack: w [128][Cin][3][3] fp32 -> wb [128][9][Cin] fp16
__global__ void wprep_kernel(const float* __restrict__ w, unsigned short* __restrict__ wb,
                             int Cin){
  int total = 128 * Cin * 9;
  for (int idx = blockIdx.x * blockDim.x + threadIdx.x; idx < total;
       idx += gridDim.x * blockDim.x){
    int ci = idx % Cin, t = (idx / Cin) % 9, co = idx / (Cin * 9);
    wb[idx] = f2h(w[((long)co * Cin + ci) * 9 + t]);
  }
}

// Implicit-GEMM MFMA conv: reflect-pad(1) 3x3, optional nearest-2x upsample, stride.
// xt [B][HWin][Cin] fp16, wb [128][9][Cin] fp16, out [B][128][HWout] fp32.
// Block = 4 waves; tile = 128 Cout x 64 spatial. grid: (HWout/64, B)
__global__ __launch_bounds__(256) void conv_mfma_kernel(
    const unsigned short* __restrict__ xt, const unsigned short* __restrict__ wb,
    float* __restrict__ out,
    int Cin, int cshift,            // cshift = log2(Cin/8)
    int Hin, int Win, int Wout, int woutLog,
    int HWin, int HWout, int stride, int upsample){
  __shared__ unsigned short Xlds[64 * 264];
  __shared__ int rowIdx[9][64];
  const int XLD = Cin + 8;
  int b = blockIdx.y;
  int sp0 = blockIdx.x * 64;
  int tid = threadIdx.x;
  int lane = tid & 63, wid = tid >> 6, lg = lane >> 4, lr = lane & 15;
  int wco0 = wid * 32;
  const unsigned short* xb = xt + (long)b * HWin * Cin;

  int VH = upsample ? 2 * Hin : Hin;
  int VW = upsample ? 2 * Win : Win;

  for (int id = tid; id < 576; id += 256){
    int tap = id >> 6, r = id & 63;
    int kh = tap / 3, kw = tap - kh * 3;
    int sp = sp0 + r;
    int oh = sp >> woutLog, ow = sp & (Wout - 1);
    int ih = oh * stride - 1 + kh;
    ih = ih < 0 ? -ih : (ih >= VH ? 2 * VH - 2 - ih : ih);
    if (upsample) ih >>= 1;
    int iw = ow * stride - 1 + kw;
    iw = iw < 0 ? -iw : (iw >= VW ? 2 * VW - 2 - iw : iw);
    if (upsample) iw >>= 1;
    rowIdx[tap][r] = ih * Win + iw;
  }

  f32x4 acc[2][4];
  #pragma unroll
  for (int m = 0; m < 2; m++)
    #pragma unroll
    for (int f = 0; f < 4; f++) acc[m][f] = (f32x4){0.f,0.f,0.f,0.f};

  int nv = Cin >> 5;
  int cmask = (1 << cshift) - 1;

  for (int tap = 0; tap < 9; tap++){
    __syncthreads();                 // protect Xlds (+ rowIdx on tap 0)
    for (int i = 0; i < nv; i++){
      int id = tid + (i << 8);
      int r = id >> cshift, ch = (id & cmask) << 3;
      *(uint4*)&Xlds[r * XLD + ch] = *(const uint4*)&xb[(long)rowIdx[tap][r] * Cin + ch];
    }
    __syncthreads();
    for (int c0 = 0; c0 < Cin; c0 += 32){
      f16x8 af[2];
      #pragma unroll
      for (int m = 0; m < 2; m++){
        const unsigned short* wp =
            wb + ((long)(wco0 + m * 16 + lr) * 9 + tap) * Cin + c0 + lg * 4;
        H8u A;
        A.u[0] = *(const ushort4*)wp;
        A.u[1] = *(const ushort4*)(wp + 16);
        af[m] = A.h;
      }
      #pragma unroll
      for (int f = 0; f < 4; f++){
        const unsigned short* xp = &Xlds[(f * 16 + lr) * XLD + c0 + lg * 4];
        H8u X;
        X.u[0] = *(const ushort4*)xp;
        X.u[1] = *(const ushort4*)(xp + 16);
        acc[0][f] = __builtin_amdgcn_mfma_f32_16x16x32_f16(af[0], X.h, acc[0][f], 0, 0, 0);
        acc[1][f] = __builtin_amdgcn_mfma_f32_16x16x32_f16(af[1], X.h, acc[1][f], 0, 0, 0);
      }
    }
  }

  float* ob = out + (long)b * 128 * HWout;
  #pragma unroll
  for (int m = 0; m < 2; m++)
    #pragma unroll
    for (int r = 0; r < 4; r++){
      int co = wco0 + m * 16 + lg * 4 + r;
      float* orow = ob + (long)co * HWout + sp0 + lr;
      orow[0]  = acc[m][0][r];
      orow[16] = acc[m][1][r];
      orow[32] = acc[m][2][r];
      orow[48] = acc[m][3][r];
    }
}

// InstanceNorm+SiLU, output fp16 TRANSPOSED for attention Q/K: outT[bh][pos][32]
__global__ void in_silu_qk_kernel(const float* __restrict__ x, unsigned short* __restrict__ outT,
                                  int HW){
  int bc = blockIdx.x;                 // b*128 + cg
  const float* p = x + (long)bc * HW;
  float s = 0.f, s2 = 0.f;
  for (int i = threadIdx.x; i < HW; i += blockDim.x){
    float v = p[i]; s += v; s2 += v * v;
  }
  block_reduce2(s, s2);
  float mean = s / (float)HW;
  float var  = s2 / (float)HW - mean * mean;
  float rstd = rsqrtf(var + EPS);
  int b = bc >> 7, cg = bc & 127, h = cg >> 5, d = cg & 31;
  unsigned short* op = outT + ((long)(b * 4 + h) * HW) * 32 + d;
  for (int i = threadIdx.x; i < HW; i += blockDim.x){
    float v = (p[i] - mean) * rstd;
    v = v * sigmoidf_(v);
    op[(long)i * 32] = f2h(v);
  }
}

// InstanceNorm+SiLU, output fp16 in channel-major layout (= V^T per head slice)
__global__ void in_silu_v_kernel(const float* __restrict__ x, unsigned short* __restrict__ out,
                                 int HW){
  int bc = blockIdx.x;
  const float* p = x + (long)bc * HW;
  float s = 0.f, s2 = 0.f;
  for (int i = threadIdx.x; i < HW; i += blockDim.x){
    float v = p[i]; s += v; s2 += v * v;
  }
  block_reduce2(s, s2);
  float mean = s / (float)HW;
  float var  = s2 / (float)HW - mean * mean;
  float rstd = rsqrtf(var + EPS);
  unsigned short* op = out + (long)bc * HW;
  for (int i = threadIdx.x; i < HW; i += blockDim.x){
    float v = (p[i] - mean) * rstd;
    op[i] = f2h(v * sigmoidf_(v));
  }
}

// MFMA flash attention (fp16). qk [bh][N][32]; v [b*128+c][N] (V^T per head).
// Output: mhaT fp16 [b][N][128] (position-major, feeds purple conv directly).
__global__ __launch_bounds__(256) void flash_attn_kernel(
    const unsigned short* __restrict__ qk,
    const unsigned short* __restrict__ vt,
    unsigned short* __restrict__ mhaT, int N){
  __shared__ __align__(16) unsigned short Klds[64 * 40];  // [key][d], stride 40
  __shared__ __align__(16) unsigned short Vlds[32 * 72];  // [d][key], stride 72
  const float SCALE = 0.17677669529663687f;               // 1/sqrt(32)

  int bh = blockIdx.y;
  int b = bh >> 2, h = bh & 3;
  int tid = threadIdx.x;
  int wid = tid >> 6, lane = tid & 63;
  int lg = lane >> 4, lr = lane & 15;
  const unsigned short* qbase = qk + (long)bh * N * 32;
  const unsigned short* vbase = vt + (long)(b * 128 + h * 32) * N;

  int q0w = blockIdx.x * 64 + wid * 16;
  f16x8 qf;
  {
    const unsigned short* qp = qbase + (long)(q0w + lr) * 32 + lg * 4;
    H8u Q;
    Q.u[0] = *(const ushort4*)qp;
    Q.u[1] = *(const ushort4*)(qp + 16);
    qf = Q.h;
  }

  float m_run = -1e30f, l_run = 0.f;
  f32x4 acc0 = {0.f,0.f,0.f,0.f}, acc1 = {0.f,0.f,0.f,0.f};

  for (int k0 = 0; k0 < N; k0 += 64){
    __syncthreads();
    {
      int key = tid >> 2, q4 = tid & 3;      // K tile: 64 keys x 32 d
      *(uint4*)(&Klds[key * 40 + q4 * 8]) =
          *(const uint4*)(qbase + (long)(k0 + key) * 32 + q4 * 8);
      int d = tid >> 3, oct = tid & 7;       // V tile: 32 d x 64 keys
      *(uint4*)(&Vlds[d * 72 + oct * 8]) =
          *(const uint4*)(vbase + (long)d * N + k0 + oct * 8);
    }
    __syncthreads();

    f32x4 st[4];
    #pragma unroll
    for (int kb = 0; kb < 4; kb++){
      const unsigned short* kp = &Klds[(kb * 16 + lr) * 40 + lg * 4];
      H8u K;
      K.u[0] = *(const ushort4*)kp;
      K.u[1] = *(const ushort4*)(kp + 16);
      st[kb] = __builtin_amdgcn_mfma_f32_16x16x32_f16(K.h, qf,
                  (f32x4){0.f,0.f,0.f,0.f}, 0, 0, 0);
    }

    float mt = -1e30f;
    #pragma unroll
    for (int kb = 0; kb < 4; kb++)
      #pragma unroll
      for (int r = 0; r < 4; r++){
        st[kb][r] *= SCALE;
        mt = fmaxf(mt, st[kb][r]);
      }
    mt = fmaxf(mt, __shfl_xor(mt, 16));
    mt = fmaxf(mt, __shfl_xor(mt, 32));
    float m_new  = fmaxf(m_run, mt);
    float fscale = __expf(m_run - m_new);
    float lt = 0.f;
    unsigned short pu[16];
    #pragma unroll
    for (int kb = 0; kb < 4; kb++)
      #pragma unroll
      for (int r = 0; r < 4; r++){
        float p = __expf(st[kb][r] - m_new);
        lt += p;
        pu[kb * 4 + r] = f2h(p);
      }
    lt += __shfl_xor(lt, 16);
    lt += __shfl_xor(lt, 32);
    l_run = l_run * fscale + lt;
    m_run = m_new;

    float fr[4];
    #pragma unroll
    for (int r = 0; r < 4; r++) fr[r] = __shfl(fscale, lg * 4 + r);
    #pragma unroll
    for (int r = 0; r < 4; r++){ acc0[r] *= fr[r]; acc1[r] *= fr[r]; }

    #pragma unroll
    for (int m = 0; m < 2; m++){
      H8e P;
      #pragma unroll
      for (int j = 0; j < 4; j++){
        P.us[j]     = pu[(2 * m) * 4 + j];
        P.us[j + 4] = pu[(2 * m + 1) * 4 + j];
      }
      const unsigned short* vp0 = &Vlds[lr * 72 + m * 32 + lg * 4];
      const unsigned short* vp1 = &Vlds[(16 + lr) * 72 + m * 32 + lg * 4];
      H8u V0, V1;
      V0.u[0] = *(const ushort4*)vp0; V0.u[1] = *(const ushort4*)(vp0 + 16);
      V1.u[0] = *(const ushort4*)vp1; V1.u[1] = *(const ushort4*)(vp1 + 16);
      acc0 = __builtin_amdgcn_mfma_f32_16x16x32_f16(P.h, V0.h, acc0, 0, 0, 0);
      acc1 = __builtin_amdgcn_mfma_f32_16x16x32_f16(P.h, V1.h, acc1, 0, 0, 0);
    }
  }

  float inv = 1.f / l_run;
  float ir[4];
  #pragma unroll
  for (int r = 0; r < 4; r++) ir[r] = __shfl(inv, lg * 4 + r);
  unsigned short* ob = mhaT + (long)b * N * 128 + h * 32;
  #pragma unroll
  for (int r = 0; r < 4; r++){
    int q = q0w + lg * 4 + r;
    ob[(long)q * 128 + lr]      = f2h(acc0[r] * ir[r]);
    ob[(long)q * 128 + 16 + lr] = f2h(acc1[r] * ir[r]);
  }
}

// Per-(b,c) sum / sumsq over HW
__global__ void stats_kernel(const float* __restrict__ x, float* __restrict__ sums,
                             float* __restrict__ sumsqs, int HW){
  long bc = blockIdx.x;
  const float* p = x + bc * HW;
  float s = 0.f, s2 = 0.f;
  for (int i = threadIdx.x; i < HW; i += blockDim.x){
    float v = p[i]; s += v; s2 += v * v;
  }
  block_reduce2(s, s2);
  if (threadIdx.x == 0){ sums[bc] = s; sumsqs[bc] = s2; }
}

__global__ void layer_reduce_kernel(const float* __restrict__ sums, const float* __restrict__ sumsqs,
                                    float* __restrict__ lsum, float* __restrict__ lsumsq, int C){
  int b = blockIdx.x;
  float s = 0.f, s2 = 0.f;
  for (int c = threadIdx.x; c < C; c += blockDim.x){
    s += sums[b * C + c]; s2 += sumsqs[b * C + c];
  }
  block_reduce2(s, s2);
  if (threadIdx.x == 0){ lsum[b] = s; lsumsq[b] = s2; }
}

__global__ void iln_finalize_kernel(const float* __restrict__ x,
                                    const float* __restrict__ sums, const float* __restrict__ sumsqs,
                                    const float* __restrict__ lsum, const float* __restrict__ lsumsq,
                                    const float* __restrict__ rho, const float* __restrict__ gamma,
                                    const float* __restrict__ beta,
                                    const float* __restrict__ gate,
                                    float* __restrict__ out,
                                    int HW, int C, int co_off, int Cout_total, int mode){
  int bc = blockIdx.y;
  int b = bc / C, c = bc % C;
  float n = (float)HW;
  float im = sums[bc] / n;
  float iv = (sumsqs[bc] / n - im * im) * (n / (n - 1.f));
  float ir = rsqrtf(iv + EPS);
  float n2 = n * (float)C;
  float lm = lsum[b] / n2;
  float lv = (lsumsq[b] / n2 - lm * lm) * (n2 / (n2 - 1.f));
  float lr = rsqrtf(lv + EPS);
  float r = rho[c], g = gamma[c], bb = beta[c];

  const float* xp = x + (long)bc * HW;
  const float* gp = gate ? gate + (long)bc * HW : nullptr;
  float* op = out + ((long)(b * Cout_total + co_off + c)) * HW;
  for (int i = blockIdx.x * blockDim.x + threadIdx.x; i < HW; i += gridDim.x * blockDim.x){
    float xv = xp[i];
    float t = r * (xv - im) * ir + (1.f - r) * (xv - lm) * lr;
    t = t * g + bb;
    float sg = sigmoidf_(t);
    op[i] = mode ? t * sg : sg * gp[i];
  }
}

extern "C" void kernel_launch(void* const* d_in, const int* in_sizes, int n_in,
                              void* d_out, int out_size, void* d_ws, size_t ws_size,
                              hipStream_t stream){
  const float* y        = (const float*)d_in[0];
  const float* s        = (const float*)d_in[1];
  const float* w_blue_s = (const float*)d_in[2];
  const float* w_blue_y = (const float*)d_in[3];
  const float* w_purple = (const float*)d_in[4];
  const float* rho_p    = (const float*)d_in[5];
  const float* gamma_p  = (const float*)d_in[6];
  const float* beta_p   = (const float*)d_in[7];
  const float* w_green  = (const float*)d_in[8];
  const float* rho_g    = (const float*)d_in[9];
  const float* gamma_g  = (const float*)d_in[10];
  const float* beta_g   = (const float*)d_in[11];
  float* out = (float*)d_out;
  float* ws  = (float*)d_ws;

  const int B = 2, SC = 128, N = 4096, NS = 16384;

  // ---- workspace layout (float units) with overlays ----
  unsigned short* s_peT = (unsigned short*)ws;             // [2][16384][128] fp16
  unsigned short* y_peT = (unsigned short*)(ws + 2097152); // [2][4096][256]  fp16
  unsigned short* yT    = (unsigned short*)(ws + 3145728); // [2][4096][256]  fp16
  float* purple_raw     = ws;                              // [2][128][16384] fp32 (overlays PE bufs)
  float* qbuf       = ws + 4194304;                        // [2][128][4096] fp32
  float* vbuf       = ws + 5242880;                        // [2][128][4096] fp32
  unsigned short* mhaT = (unsigned short*)(ws + 6291456);  // [2][4096][128] fp16
  float* green_raw  = ws + 6815744;                        // [2][128][16384] fp32
  unsigned short* qk_bf = (unsigned short*)green_raw;      // [8][4096][32] fp16 (dead before green)
  unsigned short* v_bf  = qk_bf + 1048576;                 // [2][128][4096] fp16
  unsigned short* wb_all = (unsigned short*)(ws + 11010048);
  unsigned short* wb_blue_s = wb_all;                      // 128*9*128
  unsigned short* wb_blue_y = wb_blue_s + 147456;          // 128*9*256
  unsigned short* wb_purple = wb_blue_y + 294912;          // 128*9*128
  unsigned short* wb_green  = wb_purple + 147456;          // 128*9*256
  float* stats = ws + 11452416;
  float* sumsG = stats,        *sumsqG = stats + 256;
  float* sumsP = stats + 512,  *sumsqP = stats + 768;
  float* lsumG = stats + 1024, *lsumsqG = stats + 1026;
  float* lsumP = stats + 1028, *lsumsqP = stats + 1030;

  dim3 blk(256);

  // 0) weight repack
  wprep_kernel<<<dim3(128), blk, 0, stream>>>(w_blue_s, wb_blue_s, 128);
  wprep_kernel<<<dim3(256), blk, 0, stream>>>(w_blue_y, wb_blue_y, 256);
  wprep_kernel<<<dim3(128), blk, 0, stream>>>(w_purple, wb_purple, 128);
  wprep_kernel<<<dim3(256), blk, 0, stream>>>(w_green,  wb_green,  256);

  // 1) PE + cast + transpose (and plain cast-transpose of raw y)
  pe_t_kernel<<<dim3(64, 4, B), blk, 0, stream>>>(y, y_peT, 256, N, 128, 1);
  pe_t_kernel<<<dim3(256, 2, B), blk, 0, stream>>>(s, s_peT, 128, NS, 64, 1);
  pe_t_kernel<<<dim3(64, 4, B), blk, 0, stream>>>(y, yT, 256, N, 128, 0);

  // 2) blue convs (MFMA implicit GEMM)
  conv_mfma_kernel<<<dim3(64, B), blk, 0, stream>>>(y_peT, wb_blue_y, qbuf,
      256, 5, 64, 64, 64, 6, 4096, 4096, 1, 0);
  conv_mfma_kernel<<<dim3(64, B), blk, 0, stream>>>(s_peT, wb_blue_s, vbuf,
      128, 4, 128, 128, 64, 6, 16384, 4096, 2, 0);

  // 3) instance norm + SiLU -> fp16 attention layouts
  in_silu_qk_kernel<<<dim3(B * SC), blk, 0, stream>>>(qbuf, qk_bf, N);
  in_silu_v_kernel<<<dim3(B * SC), blk, 0, stream>>>(vbuf, v_bf, N);

  // 4) MFMA flash attention -> mhaT fp16 [b][N][128]
  flash_attn_kernel<<<dim3(N / 64, B * 4), blk, 0, stream>>>(qk_bf, v_bf, mhaT, N);

  // 5) green conv: upsample2(y) 256->128 @128x128 (overwrites qk_bf/v_bf region)
  conv_mfma_kernel<<<dim3(256, B), blk, 0, stream>>>(yT, wb_green, green_raw,
      256, 5, 64, 64, 128, 7, 4096, 16384, 1, 1);

  // 6) purple conv: upsample2(mha) 128->128 @128x128 (overwrites PE region)
  conv_mfma_kernel<<<dim3(256, B), blk, 0, stream>>>(mhaT, wb_purple, purple_raw,
      128, 4, 64, 64, 128, 7, 4096, 16384, 1, 1);

  // 7) ILN stats
  stats_kernel<<<dim3(B * SC), blk, 0, stream>>>(green_raw, sumsG, sumsqG, NS);
  stats_kernel<<<dim3(B * SC), blk, 0, stream>>>(purple_raw, sumsP, sumsqP, NS);
  layer_reduce_kernel<<<dim3(B), dim3(64), 0, stream>>>(sumsG, sumsqG, lsumG, lsumsqG, SC);
  layer_reduce_kernel<<<dim3(B), dim3(64), 0, stream>>>(sumsP, sumsqP, lsumP, lsumsqP, SC);

  // 8) finalize
  iln_finalize_kernel<<<dim3(64, B * SC), blk, 0, stream>>>(purple_raw, sumsP, sumsqP,
      lsumP, lsumsqP, rho_p, gamma_p, beta_p, s, out, NS, SC, 0, 256, 0);
  iln_finalize_kernel<<<dim3(64, B * SC), blk, 0, stream>>>(green_raw, sumsG, sumsqG,
      lsumG, lsumsqG, rho_g, gamma_g, beta_g, nullptr, out, NS, SC, 128, 256, 1);
}

// Round 5
// 378.718 us; speedup vs baseline: 13.1202x; 1.0879x over previous
//
#include <hip/hip_runtime.h>
#include <math.h>

#define EPS 1e-5f

typedef __attribute__((ext_vector_type(8))) _Float16 f16x8;
typedef __attribute__((ext_vector_type(4))) float f32x4;

union H8u { ushort4 u[2]; uint4 q; f16x8 h; };

__device__ __forceinline__ float sigmoidf_(float x){ return 1.f/(1.f+__expf(-x)); }

__device__ __forceinline__ unsigned short f2h(float f){
  union { _Float16 h; unsigned short u; } c;
  c.h = (_Float16)f;            // v_cvt_f16_f32, RNE
  return c.u;
}

// block-wide reduction of two accumulators; blockDim.x must be a multiple of 64
__device__ __forceinline__ void block_reduce2(float& s, float& s2){
  __shared__ float ls[16], ls2[16];
  #pragma unroll
  for (int off = 32; off; off >>= 1){
    s  += __shfl_down(s, off);
    s2 += __shfl_down(s2, off);
  }
  int wid = threadIdx.x >> 6, lane = threadIdx.x & 63;
  int nw = blockDim.x >> 6;
  if (lane == 0){ ls[wid] = s; ls2[wid] = s2; }
  __syncthreads();
  if (threadIdx.x == 0){
    float a = ls[0], b = ls2[0];
    for (int i = 1; i < nw; i++){ a += ls[i]; b += ls2[i]; }
    ls[0] = a; ls2[0] = b;
  }
  __syncthreads();
  s = ls[0]; s2 = ls2[0];
}

// Fused (optional PE-add) + fp16 cast + transpose: x [B][C][L] fp32 -> xt [B][L][C] fp16
// grid: (L/64, C/64, B), block 256
__global__ __launch_bounds__(256) void pe_t_kernel(
    const float* __restrict__ x, unsigned short* __restrict__ xt,
    int C, int L, int half, int addpe){
  __shared__ unsigned short tile[64][72];
  int b = blockIdx.z;
  int c0 = blockIdx.y * 64, l0 = blockIdx.x * 64;
  int tid = threadIdx.x;
  const float l2r = 13.28771237954945f; // log2(10000)
  #pragma unroll
  for (int i = 0; i < 4; i++){
    int id = tid + i * 256;              // 0..1023
    int c = id >> 4, ch = (id & 15) * 4; // 64 c-rows x 16 float4 chunks (L offset)
    int cg = c0 + c;
    float4 v = *(const float4*)&x[((long)b * C + cg) * L + l0 + ch];
    float pe0 = 0.f, pe1 = 0.f, pe2 = 0.f, pe3 = 0.f;
    if (addpe){
      int d = cg < half ? cg : cg - half;
      float rate = exp2f(-l2r * (float)d / (float)half);
      float a0 = (float)(l0 + ch) * rate;
      if (cg < half){ pe0 = sinf(a0); pe1 = sinf(a0 + rate); pe2 = sinf(a0 + 2.f*rate); pe3 = sinf(a0 + 3.f*rate); }
      else          { pe0 = cosf(a0); pe1 = cosf(a0 + rate); pe2 = cosf(a0 + 2.f*rate); pe3 = cosf(a0 + 3.f*rate); }
    }
    ushort4 o;
    o.x = f2h(v.x + pe0); o.y = f2h(v.y + pe1);
    o.z = f2h(v.z + pe2); o.w = f2h(v.w + pe3);
    *(ushort4*)&tile[c][ch] = o;
  }
  __syncthreads();
  #pragma unroll
  for (int i = 0; i < 2; i++){
    int id = tid + i * 256;              // 0..511
    int l = id >> 3, ch = (id & 7) * 8;  // 64 l-rows x 8 chunks (C offset)
    ushort4 a, bq;
    a.x = tile[ch+0][l]; a.y = tile[ch+1][l]; a.z = tile[ch+2][l]; a.w = tile[ch+3][l];
    bq.x = tile[ch+4][l]; bq.y = tile[ch+5][l]; bq.z = tile[ch+6][l]; bq.w = tile[ch+7][l];
    unsigned short* op = &xt[((long)b * L + l0 + l) * C + c0 + ch];
    *(ushort4*)op = a;
    *(ushort4*)(op + 4) = bq;
  }
}

// Weight repack: w [128][Cin][3][3] fp32 -> wb [128][9][Cin] fp16
__global__ void wprep_kernel(const float* __restrict__ w, unsigned short* __restrict__ wb,
                             int Cin){
  int total = 128 * Cin * 9;
  for (int idx = blockIdx.x * blockDim.x + threadIdx.x; idx < total;
       idx += gridDim.x * blockDim.x){
    int ci = idx % Cin, t = (idx / Cin) % 9, co = idx / (Cin * 9);
    wb[idx] = f2h(w[((long)co * Cin + ci) * 9 + t]);
  }
}

// Implicit-GEMM MFMA conv: reflect-pad(1) 3x3, optional nearest-2x upsample, stride.
// xt [B][HWin][Cin] fp16, wb [128][9][Cin] fp16, out [B][128][HWout] fp32.
// Block = 4 waves; tile = 128 Cout x 64 spatial. grid: (HWout/64, B)
__global__ __launch_bounds__(256) void conv_mfma_kernel(
    const unsigned short* __restrict__ xt, const unsigned short* __restrict__ wb,
    float* __restrict__ out,
    int Cin, int cshift,            // cshift = log2(Cin/8)
    int Hin, int Win, int Wout, int woutLog,
    int HWin, int HWout, int stride, int upsample){
  __shared__ unsigned short Xlds[64 * 264];
  __shared__ int rowIdx[9][64];
  const int XLD = Cin + 8;
  int b = blockIdx.y;
  int sp0 = blockIdx.x * 64;
  int tid = threadIdx.x;
  int lane = tid & 63, wid = tid >> 6, lg = lane >> 4, lr = lane & 15;
  int wco0 = wid * 32;
  const unsigned short* xb = xt + (long)b * HWin * Cin;

  int VH = upsample ? 2 * Hin : Hin;
  int VW = upsample ? 2 * Win : Win;

  for (int id = tid; id < 576; id += 256){
    int tap = id >> 6, r = id & 63;
    int kh = tap / 3, kw = tap - kh * 3;
    int sp = sp0 + r;
    int oh = sp >> woutLog, ow = sp & (Wout - 1);
    int ih = oh * stride - 1 + kh;
    ih = ih < 0 ? -ih : (ih >= VH ? 2 * VH - 2 - ih : ih);
    if (upsample) ih >>= 1;
    int iw = ow * stride - 1 + kw;
    iw = iw < 0 ? -iw : (iw >= VW ? 2 * VW - 2 - iw : iw);
    if (upsample) iw >>= 1;
    rowIdx[tap][r] = ih * Win + iw;
  }

  f32x4 acc[2][4];
  #pragma unroll
  for (int m = 0; m < 2; m++)
    #pragma unroll
    for (int f = 0; f < 4; f++) acc[m][f] = (f32x4){0.f,0.f,0.f,0.f};

  int nv = Cin >> 5;
  int cmask = (1 << cshift) - 1;

  for (int tap = 0; tap < 9; tap++){
    __syncthreads();                 // protect Xlds (+ rowIdx on tap 0)
    for (int i = 0; i < nv; i++){
      int id = tid + (i << 8);
      int r = id >> cshift, ch = (id & cmask) << 3;
      *(uint4*)&Xlds[r * XLD + ch] = *(const uint4*)&xb[(long)rowIdx[tap][r] * Cin + ch];
    }
    __syncthreads();
    for (int c0 = 0; c0 < Cin; c0 += 32){
      f16x8 af[2];
      #pragma unroll
      for (int m = 0; m < 2; m++){
        const unsigned short* wp =
            wb + ((long)(wco0 + m * 16 + lr) * 9 + tap) * Cin + c0 + lg * 4;
        H8u A;
        A.u[0] = *(const ushort4*)wp;
        A.u[1] = *(const ushort4*)(wp + 16);
        af[m] = A.h;
      }
      #pragma unroll
      for (int f = 0; f < 4; f++){
        const unsigned short* xp = &Xlds[(f * 16 + lr) * XLD + c0 + lg * 4];
        H8u X;
        X.u[0] = *(const ushort4*)xp;
        X.u[1] = *(const ushort4*)(xp + 16);
        acc[0][f] = __builtin_amdgcn_mfma_f32_16x16x32_f16(af[0], X.h, acc[0][f], 0, 0, 0);
        acc[1][f] = __builtin_amdgcn_mfma_f32_16x16x32_f16(af[1], X.h, acc[1][f], 0, 0, 0);
      }
    }
  }

  float* ob = out + (long)b * 128 * HWout;
  #pragma unroll
  for (int m = 0; m < 2; m++)
    #pragma unroll
    for (int r = 0; r < 4; r++){
      int co = wco0 + m * 16 + lg * 4 + r;
      float* orow = ob + (long)co * HWout + sp0 + lr;
      orow[0]  = acc[m][0][r];
      orow[16] = acc[m][1][r];
      orow[32] = acc[m][2][r];
      orow[48] = acc[m][3][r];
    }
}

// InstanceNorm+SiLU, output fp16 TRANSPOSED for attention Q/K: outT[bh][pos][32]
__global__ void in_silu_qk_kernel(const float* __restrict__ x, unsigned short* __restrict__ outT,
                                  int HW){
  int bc = blockIdx.x;                 // b*128 + cg
  const float* p = x + (long)bc * HW;
  float s = 0.f, s2 = 0.f;
  for (int i = threadIdx.x; i < HW; i += blockDim.x){
    float v = p[i]; s += v; s2 += v * v;
  }
  block_reduce2(s, s2);
  float mean = s / (float)HW;
  float var  = s2 / (float)HW - mean * mean;
  float rstd = rsqrtf(var + EPS);
  int b = bc >> 7, cg = bc & 127, h = cg >> 5, d = cg & 31;
  unsigned short* op = outT + ((long)(b * 4 + h) * HW) * 32 + d;
  for (int i = threadIdx.x; i < HW; i += blockDim.x){
    float v = (p[i] - mean) * rstd;
    v = v * sigmoidf_(v);
    op[(long)i * 32] = f2h(v);
  }
}

// InstanceNorm+SiLU, output fp16 in channel-major layout (= V^T per head slice)
__global__ void in_silu_v_kernel(const float* __restrict__ x, unsigned short* __restrict__ out,
                                 int HW){
  int bc = blockIdx.x;
  const float* p = x + (long)bc * HW;
  float s = 0.f, s2 = 0.f;
  for (int i = threadIdx.x; i < HW; i += blockDim.x){
    float v = p[i]; s += v; s2 += v * v;
  }
  block_reduce2(s, s2);
  float mean = s / (float)HW;
  float var  = s2 / (float)HW - mean * mean;
  float rstd = rsqrtf(var + EPS);
  unsigned short* op = out + (long)bc * HW;
  for (int i = threadIdx.x; i < HW; i += blockDim.x){
    float v = (p[i] - mean) * rstd;
    op[i] = f2h(v * sigmoidf_(v));
  }
}

// MFMA flash attention (fp16), 4-way key-split in one 1024-thread block.
// 16 waves = 4 query-groups (qg) x 4 key-splits (ks). Wave: 16 queries x N/4 keys.
// LDS K/V tiles stored in MFMA-fragment order -> all hot reads are ds_read_b128
// at base+lane*16 (conflict-free). Final split-merge done in LDS.
// qk [bh][N][32]; v [b*128+c][N]; out mhaT fp16 [b][N][128].
__global__ __launch_bounds__(1024, 8) void flash_attn_kernel(
    const unsigned short* __restrict__ qk,
    const unsigned short* __restrict__ vt,
    unsigned short* __restrict__ mhaT, int N){
  __shared__ float smem[9216];                 // 36 KB, staging & merge overlap
  unsigned short* sstage = (unsigned short*)smem;
  const float SCALE = 0.17677669529663687f;    // 1/sqrt(32)

  int bh = blockIdx.y;
  int b = bh >> 2, h = bh & 3;
  int tid = threadIdx.x;
  int ks = tid >> 8;                 // key-split 0..3 (contiguous 256-thread group)
  int t256 = tid & 255;
  int qg = (tid >> 6) & 3;           // query-group within split
  int lane = tid & 63;
  int lg = lane >> 4, lr = lane & 15;
  const unsigned short* qbase = qk + (long)bh * N * 32;
  const unsigned short* vbase = vt + (long)(b * 128 + h * 32) * N;
  int ksu = ks * 4096;               // ushort offset of this split's 8KB stage

  // Q fragment: queries q0w..q0w+15
  int q0w = blockIdx.x * 64 + qg * 16;
  f16x8 qf;
  {
    const unsigned short* qp = qbase + (long)(q0w + lr) * 32 + lg * 4;
    H8u Q;
    Q.u[0] = *(const ushort4*)qp;
    Q.u[1] = *(const ushort4*)(qp + 16);
    qf = Q.h;
  }

  // staging dest precompute (constant per thread)
  int skey = t256 >> 2, sq4 = t256 & 3;        // K: key row, d-quarter
  int kdst = ksu + (((skey >> 4) * 4 + (sq4 & 1) * 2) * 16 + (skey & 15)) * 8 + (sq4 >> 1) * 4;
  int sd = t256 >> 3, soct = t256 & 7;         // V: d row, key-octet
  int vdst = ksu + 2048 +
      ((((soct >> 2) * 2 + (sd >> 4)) * 4 + (soct & 1) * 2) * 16 + (sd & 15)) * 8 +
      ((soct >> 1) & 1) * 4;

  float m_run = -1e30f, l_run = 0.f;
  f32x4 acc0 = {0.f,0.f,0.f,0.f}, acc1 = {0.f,0.f,0.f,0.f};

  const int NT = N >> 8;                       // tiles per split (N/4/64)
  for (int t = 0; t < NT; t++){
    int k0 = (ks * NT + t) * 64;
    __syncthreads();
    {
      uint4 kl = *(const uint4*)(qbase + (long)(k0 + skey) * 32 + sq4 * 8);
      uint2 ka; ka.x = kl.x; ka.y = kl.y;
      uint2 kb2; kb2.x = kl.z; kb2.y = kl.w;
      *(uint2*)(&sstage[kdst])       = ka;
      *(uint2*)(&sstage[kdst + 128]) = kb2;    // next lg group (+16 lanes * 8 ushorts)
      uint4 vl = *(const uint4*)(vbase + (long)sd * N + k0 + soct * 8);
      uint2 va; va.x = vl.x; va.y = vl.y;
      uint2 vb2; vb2.x = vl.z; vb2.y = vl.w;
      *(uint2*)(&sstage[vdst])       = va;
      *(uint2*)(&sstage[vdst + 128]) = vb2;
    }
    __syncthreads();

    // S^T: 4 x mfma(K-frag, Q-frag); st[kb][r] = S[key kb*16+lg*4+r][query lr]
    f32x4 st[4];
    #pragma unroll
    for (int kb = 0; kb < 4; kb++){
      H8u K;
      K.q = *(const uint4*)(&sstage[ksu + (kb * 64 + lane) * 8]);
      st[kb] = __builtin_amdgcn_mfma_f32_16x16x32_f16(K.h, qf,
                  (f32x4){0.f,0.f,0.f,0.f}, 0, 0, 0);
    }

    float mt = -1e30f;
    #pragma unroll
    for (int kb = 0; kb < 4; kb++)
      #pragma unroll
      for (int r = 0; r < 4; r++){
        st[kb][r] *= SCALE;
        mt = fmaxf(mt, st[kb][r]);
      }
    mt = fmaxf(mt, __shfl_xor(mt, 16));
    mt = fmaxf(mt, __shfl_xor(mt, 32));
    float m_new  = fmaxf(m_run, mt);
    float fscale = __expf(m_run - m_new);
    float lt = 0.f;
    unsigned int pup[8];                       // P packed fp16x2, index kb*2+(r>>1)
    #pragma unroll
    for (int kb = 0; kb < 4; kb++)
      #pragma unroll
      for (int rp = 0; rp < 2; rp++){
        float p0 = __expf(st[kb][2*rp]   - m_new);
        float p1 = __expf(st[kb][2*rp+1] - m_new);
        lt += p0 + p1;
        pup[kb * 2 + rp] = (unsigned int)f2h(p0) | ((unsigned int)f2h(p1) << 16);
      }
    lt += __shfl_xor(lt, 16);
    lt += __shfl_xor(lt, 32);
    l_run = l_run * fscale + lt;
    m_run = m_new;

    float fr[4];
    #pragma unroll
    for (int r = 0; r < 4; r++) fr[r] = __shfl(fscale, lg * 4 + r);
    #pragma unroll
    for (int r = 0; r < 4; r++){ acc0[r] *= fr[r]; acc1[r] *= fr[r]; }

    // PV: A = P (k = keys m*32..), B = V-frag; pup[4m..4m+3] is exactly the A-frag
    #pragma unroll
    for (int m = 0; m < 2; m++){
      H8u P, V0, V1;
      P.q.x = pup[4*m]; P.q.y = pup[4*m+1]; P.q.z = pup[4*m+2]; P.q.w = pup[4*m+3];
      V0.q = *(const uint4*)(&sstage[ksu + 2048 + ((m * 2 + 0) * 64 + lane) * 8]);
      V1.q = *(const uint4*)(&sstage[ksu + 2048 + ((m * 2 + 1) * 64 + lane) * 8]);
      acc0 = __builtin_amdgcn_mfma_f32_16x16x32_f16(P.h, V0.h, acc0, 0, 0, 0);
      acc1 = __builtin_amdgcn_mfma_f32_16x16x32_f16(P.h, V1.h, acc1, 0, 0, 0);
    }
  }

  // ---- split merge in LDS ----
  __syncthreads();
  float* accM = smem;                          // [qg][ks][16 q][33]
  float* mM   = smem + 8448;                   // [qg][ks][16]
  float* lM   = smem + 8704;                   // [qg][ks][16]
  #pragma unroll
  for (int r = 0; r < 4; r++){
    accM[((qg * 4 + ks) * 16 + (lg * 4 + r)) * 33 + lr]      = acc0[r];
    accM[((qg * 4 + ks) * 16 + (lg * 4 + r)) * 33 + 16 + lr] = acc1[r];
  }
  if (lg == 0){
    mM[(qg * 4 + ks) * 16 + lr] = m_run;
    lM[(qg * 4 + ks) * 16 + lr] = l_run;
  }
  __syncthreads();
  if (ks == 0){
    int q = lane >> 2, dc = lane & 3;          // 16 queries x 4 d-chunks of 8
    float ms[4], es[4];
    float m = -1e30f;
    #pragma unroll
    for (int s = 0; s < 4; s++){ ms[s] = mM[(qg * 4 + s) * 16 + q]; m = fmaxf(m, ms[s]); }
    float l = 0.f;
    #pragma unroll
    for (int s = 0; s < 4; s++){ es[s] = __expf(ms[s] - m); l += lM[(qg * 4 + s) * 16 + q] * es[s]; }
    float inv = 1.f / l;
    float o[8];
    #pragma unroll
    for (int j = 0; j < 8; j++) o[j] = 0.f;
    #pragma unroll
    for (int s = 0; s < 4; s++){
      const float* ap = &accM[((qg * 4 + s) * 16 + q) * 33 + dc * 8];
      #pragma unroll
      for (int j = 0; j < 8; j++) o[j] += ap[j] * es[s];
    }
    ushort4 o0, o1;
    o0.x = f2h(o[0]*inv); o0.y = f2h(o[1]*inv); o0.z = f2h(o[2]*inv); o0.w = f2h(o[3]*inv);
    o1.x = f2h(o[4]*inv); o1.y = f2h(o[5]*inv); o1.z = f2h(o[6]*inv); o1.w = f2h(o[7]*inv);
    unsigned short* op = &mhaT[((long)b * N + q0w + q) * 128 + h * 32 + dc * 8];
    *(ushort4*)op = o0;
    *(ushort4*)(op + 4) = o1;
  }
}

// Per-(b,c) sum / sumsq over HW
__global__ void stats_kernel(const float* __restrict__ x, float* __restrict__ sums,
                             float* __restrict__ sumsqs, int HW){
  long bc = blockIdx.x;
  const float* p = x + bc * HW;
  float s = 0.f, s2 = 0.f;
  for (int i = threadIdx.x; i < HW; i += blockDim.x){
    float v = p[i]; s += v; s2 += v * v;
  }
  block_reduce2(s, s2);
  if (threadIdx.x == 0){ sums[bc] = s; sumsqs[bc] = s2; }
}

__global__ void layer_reduce_kernel(const float* __restrict__ sums, const float* __restrict__ sumsqs,
                                    float* __restrict__ lsum, float* __restrict__ lsumsq, int C){
  int b = blockIdx.x;
  float s = 0.f, s2 = 0.f;
  for (int c = threadIdx.x; c < C; c += blockDim.x){
    s += sums[b * C + c]; s2 += sumsqs[b * C + c];
  }
  block_reduce2(s, s2);
  if (threadIdx.x == 0){ lsum[b] = s; lsumsq[b] = s2; }
}

__global__ void iln_finalize_kernel(const float* __restrict__ x,
                                    const float* __restrict__ sums, const float* __restrict__ sumsqs,
                                    const float* __restrict__ lsum, const float* __restrict__ lsumsq,
                                    const float* __restrict__ rho, const float* __restrict__ gamma,
                                    const float* __restrict__ beta,
                                    const float* __restrict__ gate,
                                    float* __restrict__ out,
                                    int HW, int C, int co_off, int Cout_total, int mode){
  int bc = blockIdx.y;
  int b = bc / C, c = bc % C;
  float n = (float)HW;
  float im = sums[bc] / n;
  float iv = (sumsqs[bc] / n - im * im) * (n / (n - 1.f));
  float ir = rsqrtf(iv + EPS);
  float n2 = n * (float)C;
  float lm = lsum[b] / n2;
  float lv = (lsumsq[b] / n2 - lm * lm) * (n2 / (n2 - 1.f));
  float lr = rsqrtf(lv + EPS);
  float r = rho[c], g = gamma[c], bb = beta[c];

  const float* xp = x + (long)bc * HW;
  const float* gp = gate ? gate + (long)bc * HW : nullptr;
  float* op = out + ((long)(b * Cout_total + co_off + c)) * HW;
  for (int i = blockIdx.x * blockDim.x + threadIdx.x; i < HW; i += gridDim.x * blockDim.x){
    float xv = xp[i];
    float t = r * (xv - im) * ir + (1.f - r) * (xv - lm) * lr;
    t = t * g + bb;
    float sg = sigmoidf_(t);
    op[i] = mode ? t * sg : sg * gp[i];
  }
}

extern "C" void kernel_launch(void* const* d_in, const int* in_sizes, int n_in,
                              void* d_out, int out_size, void* d_ws, size_t ws_size,
                              hipStream_t stream){
  const float* y        = (const float*)d_in[0];
  const float* s        = (const float*)d_in[1];
  const float* w_blue_s = (const float*)d_in[2];
  const float* w_blue_y = (const float*)d_in[3];
  const float* w_purple = (const float*)d_in[4];
  const float* rho_p    = (const float*)d_in[5];
  const float* gamma_p  = (const float*)d_in[6];
  const float* beta_p   = (const float*)d_in[7];
  const float* w_green  = (const float*)d_in[8];
  const float* rho_g    = (const float*)d_in[9];
  const float* gamma_g  = (const float*)d_in[10];
  const float* beta_g   = (const float*)d_in[11];
  float* out = (float*)d_out;
  float* ws  = (float*)d_ws;

  const int B = 2, SC = 128, N = 4096, NS = 16384;

  // ---- workspace layout (float units) with overlays ----
  unsigned short* s_peT = (unsigned short*)ws;             // [2][16384][128] fp16
  unsigned short* y_peT = (unsigned short*)(ws + 2097152); // [2][4096][256]  fp16
  unsigned short* yT    = (unsigned short*)(ws + 3145728); // [2][4096][256]  fp16
  float* purple_raw     = ws;                              // [2][128][16384] fp32 (overlays PE bufs)
  float* qbuf       = ws + 4194304;                        // [2][128][4096] fp32
  float* vbuf       = ws + 5242880;                        // [2][128][4096] fp32
  unsigned short* mhaT = (unsigned short*)(ws + 6291456);  // [2][4096][128] fp16
  float* green_raw  = ws + 6815744;                        // [2][128][16384] fp32
  unsigned short* qk_bf = (unsigned short*)green_raw;      // [8][4096][32] fp16 (dead before green)
  unsigned short* v_bf  = qk_bf + 1048576;                 // [2][128][4096] fp16
  unsigned short* wb_all = (unsigned short*)(ws + 11010048);
  unsigned short* wb_blue_s = wb_all;                      // 128*9*128
  unsigned short* wb_blue_y = wb_blue_s + 147456;          // 128*9*256
  unsigned short* wb_purple = wb_blue_y + 294912;          // 128*9*128
  unsigned short* wb_green  = wb_purple + 147456;          // 128*9*256
  float* stats = ws + 11452416;
  float* sumsG = stats,        *sumsqG = stats + 256;
  float* sumsP = stats + 512,  *sumsqP = stats + 768;
  float* lsumG = stats + 1024, *lsumsqG = stats + 1026;
  float* lsumP = stats + 1028, *lsumsqP = stats + 1030;

  dim3 blk(256);

  // 0) weight repack
  wprep_kernel<<<dim3(128), blk, 0, stream>>>(w_blue_s, wb_blue_s, 128);
  wprep_kernel<<<dim3(256), blk, 0, stream>>>(w_blue_y, wb_blue_y, 256);
  wprep_kernel<<<dim3(128), blk, 0, stream>>>(w_purple, wb_purple, 128);
  wprep_kernel<<<dim3(256), blk, 0, stream>>>(w_green,  wb_green,  256);

  // 1) PE + cast + transpose (and plain cast-transpose of raw y)
  pe_t_kernel<<<dim3(64, 4, B), blk, 0, stream>>>(y, y_peT, 256, N, 128, 1);
  pe_t_kernel<<<dim3(256, 2, B), blk, 0, stream>>>(s, s_peT, 128, NS, 64, 1);
  pe_t_kernel<<<dim3(64, 4, B), blk, 0, stream>>>(y, yT, 256, N, 128, 0);

  // 2) blue convs (MFMA implicit GEMM)
  conv_mfma_kernel<<<dim3(64, B), blk, 0, stream>>>(y_peT, wb_blue_y, qbuf,
      256, 5, 64, 64, 64, 6, 4096, 4096, 1, 0);
  conv_mfma_kernel<<<dim3(64, B), blk, 0, stream>>>(s_peT, wb_blue_s, vbuf,
      128, 4, 128, 128, 64, 6, 16384, 4096, 2, 0);

  // 3) instance norm + SiLU -> fp16 attention layouts
  in_silu_qk_kernel<<<dim3(B * SC), blk, 0, stream>>>(qbuf, qk_bf, N);
  in_silu_v_kernel<<<dim3(B * SC), blk, 0, stream>>>(vbuf, v_bf, N);

  // 4) MFMA flash attention (4-way key split, LDS merge) -> mhaT fp16 [b][N][128]
  flash_attn_kernel<<<dim3(N / 64, B * 4), dim3(1024), 0, stream>>>(qk_bf, v_bf, mhaT, N);

  // 5) green conv: upsample2(y) 256->128 @128x128 (overwrites qk_bf/v_bf region)
  conv_mfma_kernel<<<dim3(256, B), blk, 0, stream>>>(yT, wb_green, green_raw,
      256, 5, 64, 64, 128, 7, 4096, 16384, 1, 1);

  // 6) purple conv: upsample2(mha) 128->128 @128x128 (overwrites PE region)
  conv_mfma_kernel<<<dim3(256, B), blk, 0, stream>>>(mhaT, wb_purple, purple_raw,
      128, 4, 64, 64, 128, 7, 4096, 16384, 1, 1);

  // 7) ILN stats
  stats_kernel<<<dim3(B * SC), blk, 0, stream>>>(green_raw, sumsG, sumsqG, NS);
  stats_kernel<<<dim3(B * SC), blk, 0, stream>>>(purple_raw, sumsP, sumsqP, NS);
  layer_reduce_kernel<<<dim3(B), dim3(64), 0, stream>>>(sumsG, sumsqG, lsumG, lsumsqG, SC);
  layer_reduce_kernel<<<dim3(B), dim3(64), 0, stream>>>(sumsP, sumsqP, lsumP, lsumsqP, SC);

  // 8) finalize
  iln_finalize_kernel<<<dim3(64, B * SC), blk, 0, stream>>>(purple_raw, sumsP, sumsqP,
      lsumP, lsumsqP, rho_p, gamma_p, beta_p, s, out, NS, SC, 0, 256, 0);
  iln_finalize_kernel<<<dim3(64, B * SC), blk, 0, stream>>>(green_raw, sumsG, sumsqG,
      lsumG, lsumsqG, rho_g, gamma_g, beta_g, nullptr, out, NS, SC, 128, 256, 1);
}

// Round 6
// 249.853 us; speedup vs baseline: 19.8872x; 1.5158x over previous
//
#include <hip/hip_runtime.h>
#include <math.h>

#define EPS 1e-5f

typedef __attribute__((ext_vector_type(8))) _Float16 f16x8;
typedef __attribute__((ext_vector_type(4))) float f32x4;

union H8u { ushort4 u[2]; uint4 q; f16x8 h; };

__device__ __forceinline__ float sigmoidf_(float x){ return 1.f/(1.f+__expf(-x)); }

__device__ __forceinline__ unsigned short f2h(float f){
  union { _Float16 h; unsigned short u; } c;
  c.h = (_Float16)f;            // v_cvt_f16_f32, RNE
  return c.u;
}

// block-wide reduction of two accumulators; blockDim.x must be a multiple of 64
__device__ __forceinline__ void block_reduce2(float& s, float& s2){
  __shared__ float ls[16], ls2[16];
  #pragma unroll
  for (int off = 32; off; off >>= 1){
    s  += __shfl_down(s, off);
    s2 += __shfl_down(s2, off);
  }
  int wid = threadIdx.x >> 6, lane = threadIdx.x & 63;
  int nw = blockDim.x >> 6;
  if (lane == 0){ ls[wid] = s; ls2[wid] = s2; }
  __syncthreads();
  if (threadIdx.x == 0){
    float a = ls[0], b = ls2[0];
    for (int i = 1; i < nw; i++){ a += ls[i]; b += ls2[i]; }
    ls[0] = a; ls2[0] = b;
  }
  __syncthreads();
  s = ls[0]; s2 = ls2[0];
}

// Fused (optional PE-add) + fp16 cast + transpose: x [B][C][L] fp32 -> xt [B][L][C] fp16
__global__ __launch_bounds__(256) void pe_t_kernel(
    const float* __restrict__ x, unsigned short* __restrict__ xt,
    int C, int L, int half, int addpe){
  __shared__ unsigned short tile[64][72];
  int b = blockIdx.z;
  int c0 = blockIdx.y * 64, l0 = blockIdx.x * 64;
  int tid = threadIdx.x;
  const float l2r = 13.28771237954945f; // log2(10000)
  #pragma unroll
  for (int i = 0; i < 4; i++){
    int id = tid + i * 256;
    int c = id >> 4, ch = (id & 15) * 4;
    int cg = c0 + c;
    float4 v = *(const float4*)&x[((long)b * C + cg) * L + l0 + ch];
    float pe0 = 0.f, pe1 = 0.f, pe2 = 0.f, pe3 = 0.f;
    if (addpe){
      int d = cg < half ? cg : cg - half;
      float rate = exp2f(-l2r * (float)d / (float)half);
      float a0 = (float)(l0 + ch) * rate;
      if (cg < half){ pe0 = sinf(a0); pe1 = sinf(a0 + rate); pe2 = sinf(a0 + 2.f*rate); pe3 = sinf(a0 + 3.f*rate); }
      else          { pe0 = cosf(a0); pe1 = cosf(a0 + rate); pe2 = cosf(a0 + 2.f*rate); pe3 = cosf(a0 + 3.f*rate); }
    }
    ushort4 o;
    o.x = f2h(v.x + pe0); o.y = f2h(v.y + pe1);
    o.z = f2h(v.z + pe2); o.w = f2h(v.w + pe3);
    *(ushort4*)&tile[c][ch] = o;
  }
  __syncthreads();
  #pragma unroll
  for (int i = 0; i < 2; i++){
    int id = tid + i * 256;
    int l = id >> 3, ch = (id & 7) * 8;
    ushort4 a, bq;
    a.x = tile[ch+0][l]; a.y = tile[ch+1][l]; a.z = tile[ch+2][l]; a.w = tile[ch+3][l];
    bq.x = tile[ch+4][l]; bq.y = tile[ch+5][l]; bq.z = tile[ch+6][l]; bq.w = tile[ch+7][l];
    unsigned short* op = &xt[((long)b * L + l0 + l) * C + c0 + ch];
    *(ushort4*)op = a;
    *(ushort4*)(op + 4) = bq;
  }
}

// Plain weights -> fragment-ordered fp16: [coB(8)][9][NCHUNK][64 lanes][8]
__global__ void wffP_kernel(const float* __restrict__ w, unsigned short* __restrict__ o, int Cin){
  int NCH = Cin >> 5;
  int per_tap = NCH << 9;
  int total = 8 * 9 * per_tap;
  for (int idx = blockIdx.x * blockDim.x + threadIdx.x; idx < total;
       idx += gridDim.x * blockDim.x){
    int e = idx & 7, lane = (idx >> 3) & 63, chunk = (idx >> 9) % NCH;
    int tap = (idx / per_tap) % 9, coB = idx / (9 * per_tap);
    int lg = lane >> 4, lr = lane & 15;
    int co = coB * 16 + lr;
    int ch = chunk * 32 + ((e < 4) ? lg * 4 + e : 16 + lg * 4 + e - 4);
    o[idx] = f2h(w[((long)co * Cin + ch) * 9 + tap]);
  }
}

// Parity-folded upsample weights -> fragment order: [p(4)][coB(8)][4 tap][NCHUNK][64][8]
// eff2[kr][kc] = sum of 3x3 taps folding onto the same input pixel for parity (ph,pw)
__global__ void wffF_kernel(const float* __restrict__ w, unsigned short* __restrict__ o, int Cin){
  int NCH = Cin >> 5;
  int per_tap = NCH << 9;
  int per_p = 8 * 4 * per_tap;
  int total = 4 * per_p;
  for (int idx = blockIdx.x * blockDim.x + threadIdx.x; idx < total;
       idx += gridDim.x * blockDim.x){
    int e = idx & 7, lane = (idx >> 3) & 63, chunk = (idx >> 9) % NCH;
    int tap = (idx / per_tap) % 4;
    int coB = (idx / (4 * per_tap)) % 8;
    int p = idx / per_p;
    int ph = p >> 1, pw = p & 1, kr = tap >> 1, kc = tap & 1;
    int lg = lane >> 4, lr = lane & 15;
    int co = coB * 16 + lr;
    int ch = chunk * 32 + ((e < 4) ? lg * 4 + e : 16 + lg * 4 + e - 4);
    const float* wb = &w[((long)co * Cin + ch) * 9];
    float sum = 0.f;
    for (int kh = 0; kh < 3; kh++){
      bool rok = (ph == 0) ? (kr == 0 ? kh == 0 : kh >= 1)
                           : (kr == 0 ? kh <= 1 : kh == 2);
      if (!rok) continue;
      for (int kw = 0; kw < 3; kw++){
        bool cok = (pw == 0) ? (kc == 0 ? kw == 0 : kw >= 1)
                             : (kc == 0 ? kw <= 1 : kw == 2);
        if (cok) sum += wb[kh * 3 + kw];
      }
    }
    o[idx] = f2h(sum);
  }
}

// Unified implicit-GEMM MFMA conv. Block = 4 waves, tile = 64co x 64sp.
// UP=1: parity-folded 2x2 taps on nearest-2x-upsampled reflect-pad grid
//       (grid: x=Hin parity-rows, y=2 co-halves, z=B*4 parities)
// UP=0: 3x3 reflect-pad, stride 1/2 (grid: x=HWout/64, y=2, z=B)
// xt [B][Hin*Win][Cin] fp16, wff fragment-ordered, out [B][128][HWout] fp32.
// LDS X tiles in MFMA-fragment order: every B-frag read = ds_read_b128 at
// base+lane*16 (conflict-free); +16B/chunk skew de-conflicts staging writes.
template<int NTAP, int CSHIFT, int UP>
__global__ __launch_bounds__(256) void conv_tile_kernel(
    const unsigned short* __restrict__ xt, const unsigned short* __restrict__ wff,
    float* __restrict__ out,
    int Hin, int Win, int stride, int Wout, int woutLog, int HWout){
  constexpr int Cin = 8 << CSHIFT;
  constexpr int NCHUNK = 1 << (CSHIFT - 2);
  __shared__ __align__(16) char stage[NCHUNK * 4112];
  __shared__ int rowIdx[NTAP][64];
  int tid = threadIdx.x;
  int lane = tid & 63, wid = tid >> 6;
  int lg = lane >> 4, lr = lane & 15;
  int b, par = 0;
  if (UP){ par = blockIdx.z & 3; b = blockIdx.z >> 2; } else b = blockIdx.z;
  const unsigned short* xb = xt + (long)b * Hin * Win * Cin;
  int coB = blockIdx.y * 4 + wid;

  if (UP){
    int ph = par >> 1, pw = par & 1;
    int ii = blockIdx.x;
    int VH = 2 * Hin, VW = 2 * Win;
    for (int id = tid; id < NTAP * 64; id += 256){
      int tap = id >> 6, r = id & 63;
      int kr = tap >> 1, kc = tap & 1;
      int v = 2 * ii + (ph == 0 ? (kr == 0 ? -1 : 0) : (kr == 0 ? 0 : 2));
      v = v < 0 ? -v : (v >= VH ? 2 * VH - 2 - v : v);
      int u = 2 * r + (pw == 0 ? (kc == 0 ? -1 : 0) : (kc == 0 ? 0 : 2));
      u = u < 0 ? -u : (u >= VW ? 2 * VW - 2 - u : u);
      rowIdx[tap][r] = (v >> 1) * Win + (u >> 1);
    }
  } else {
    int sp0 = blockIdx.x * 64;
    for (int id = tid; id < NTAP * 64; id += 256){
      int tap = id >> 6, r = id & 63;
      int kh = tap / 3, kw = tap - kh * 3;
      int sp = sp0 + r;
      int oh = sp >> woutLog, ow = sp & (Wout - 1);
      int ih = oh * stride - 1 + kh;
      ih = ih < 0 ? -ih : (ih >= Hin ? 2 * Hin - 2 - ih : ih);
      int iw = ow * stride - 1 + kw;
      iw = iw < 0 ? -iw : (iw >= Win ? 2 * Win - 2 - iw : iw);
      rowIdx[tap][r] = ih * Win + iw;
    }
  }

  f32x4 acc[4];
  #pragma unroll
  for (int f = 0; f < 4; f++) acc[f] = (f32x4){0.f, 0.f, 0.f, 0.f};

  const unsigned short* wbase =
      wff + ((long)((UP ? par : 0) * 8 + coB) * NTAP) * (NCHUNK * 512) + lane * 8;

  for (int tap = 0; tap < NTAP; tap++){
    __syncthreads();
    #pragma unroll
    for (int i2 = 0; i2 < NCHUNK; i2++){
      int id = tid + (i2 << 8);
      int sp = id >> CSHIFT;
      int c8 = (id & ((1 << CSHIFT) - 1)) << 3;
      int chunk = c8 >> 5, c = c8 & 31;
      int lgb = (c & 15) >> 2, hoff = (c >> 4) & 1;
      uint4 g = *(const uint4*)&xb[(long)rowIdx[tap][sp] * Cin + c8];
      int slot = ((chunk * 4 + (sp >> 4)) * 64 + lgb * 16 + (sp & 15)) * 16
                 + hoff * 8 + chunk * 16;
      *(uint2*)(stage + slot)       = make_uint2(g.x, g.y);
      *(uint2*)(stage + slot + 256) = make_uint2(g.z, g.w);
    }
    __syncthreads();
    const unsigned short* wp = wbase + (long)tap * (NCHUNK * 512);
    #pragma unroll
    for (int ch = 0; ch < NCHUNK; ch++){
      H8u A; A.q = *(const uint4*)(wp + ch * 512);
      #pragma unroll
      for (int f = 0; f < 4; f++){
        H8u X; X.q = *(const uint4*)(stage + ((ch * 4 + f) * 64 + lane) * 16 + ch * 16);
        acc[f] = __builtin_amdgcn_mfma_f32_16x16x32_f16(A.h, X.h, acc[f], 0, 0, 0);
      }
    }
  }

  float* ob = out + (long)b * 128 * HWout;
  #pragma unroll
  for (int f = 0; f < 4; f++){
    int spl = f * 16 + lr;
    long opos;
    if (UP){
      int oh = 2 * blockIdx.x + (par >> 1);
      int ow = 2 * spl + (par & 1);
      opos = (long)oh * Wout + ow;
    } else opos = (long)blockIdx.x * 64 + spl;
    #pragma unroll
    for (int r = 0; r < 4; r++){
      int co = coB * 16 + lg * 4 + r;
      ob[(long)co * HWout + opos] = acc[f][r];
    }
  }
}

// InstanceNorm+SiLU, output fp16 TRANSPOSED for attention Q/K: outT[bh][pos][32]
__global__ void in_silu_qk_kernel(const float* __restrict__ x, unsigned short* __restrict__ outT,
                                  int HW){
  int bc = blockIdx.x;
  const float* p = x + (long)bc * HW;
  float s = 0.f, s2 = 0.f;
  for (int i = threadIdx.x; i < HW; i += blockDim.x){
    float v = p[i]; s += v; s2 += v * v;
  }
  block_reduce2(s, s2);
  float mean = s / (float)HW;
  float var  = s2 / (float)HW - mean * mean;
  float rstd = rsqrtf(var + EPS);
  int b = bc >> 7, cg = bc & 127, h = cg >> 5, d = cg & 31;
  unsigned short* op = outT + ((long)(b * 4 + h) * HW) * 32 + d;
  for (int i = threadIdx.x; i < HW; i += blockDim.x){
    float v = (p[i] - mean) * rstd;
    v = v * sigmoidf_(v);
    op[(long)i * 32] = f2h(v);
  }
}

// InstanceNorm+SiLU, output fp16 in channel-major layout (= V^T per head slice)
__global__ void in_silu_v_kernel(const float* __restrict__ x, unsigned short* __restrict__ out,
                                 int HW){
  int bc = blockIdx.x;
  const float* p = x + (long)bc * HW;
  float s = 0.f, s2 = 0.f;
  for (int i = threadIdx.x; i < HW; i += blockDim.x){
    float v = p[i]; s += v; s2 += v * v;
  }
  block_reduce2(s, s2);
  float mean = s / (float)HW;
  float var  = s2 / (float)HW - mean * mean;
  float rstd = rsqrtf(var + EPS);
  unsigned short* op = out + (long)bc * HW;
  for (int i = threadIdx.x; i < HW; i += blockDim.x){
    float v = (p[i] - mean) * rstd;
    op[i] = f2h(v * sigmoidf_(v));
  }
}

// MFMA flash attention (fp16), 4-way key-split in one 1024-thread block.
__global__ __launch_bounds__(1024, 8) void flash_attn_kernel(
    const unsigned short* __restrict__ qk,
    const unsigned short* __restrict__ vt,
    unsigned short* __restrict__ mhaT, int N){
  __shared__ float smem[9216];
  unsigned short* sstage = (unsigned short*)smem;
  const float SCALE = 0.17677669529663687f;

  int bh = blockIdx.y;
  int b = bh >> 2, h = bh & 3;
  int tid = threadIdx.x;
  int ks = tid >> 8;
  int t256 = tid & 255;
  int qg = (tid >> 6) & 3;
  int lane = tid & 63;
  int lg = lane >> 4, lr = lane & 15;
  const unsigned short* qbase = qk + (long)bh * N * 32;
  const unsigned short* vbase = vt + (long)(b * 128 + h * 32) * N;
  int ksu = ks * 4096;

  int q0w = blockIdx.x * 64 + qg * 16;
  f16x8 qf;
  {
    const unsigned short* qp = qbase + (long)(q0w + lr) * 32 + lg * 4;
    H8u Q;
    Q.u[0] = *(const ushort4*)qp;
    Q.u[1] = *(const ushort4*)(qp + 16);
    qf = Q.h;
  }

  int skey = t256 >> 2, sq4 = t256 & 3;
  int kdst = ksu + (((skey >> 4) * 4 + (sq4 & 1) * 2) * 16 + (skey & 15)) * 8 + (sq4 >> 1) * 4;
  int sd = t256 >> 3, soct = t256 & 7;
  int vdst = ksu + 2048 +
      ((((soct >> 2) * 2 + (sd >> 4)) * 4 + (soct & 1) * 2) * 16 + (sd & 15)) * 8 +
      ((soct >> 1) & 1) * 4;

  float m_run = -1e30f, l_run = 0.f;
  f32x4 acc0 = {0.f,0.f,0.f,0.f}, acc1 = {0.f,0.f,0.f,0.f};

  const int NT = N >> 8;
  for (int t = 0; t < NT; t++){
    int k0 = (ks * NT + t) * 64;
    __syncthreads();
    {
      uint4 kl = *(const uint4*)(qbase + (long)(k0 + skey) * 32 + sq4 * 8);
      *(uint2*)(&sstage[kdst])       = make_uint2(kl.x, kl.y);
      *(uint2*)(&sstage[kdst + 128]) = make_uint2(kl.z, kl.w);
      uint4 vl = *(const uint4*)(vbase + (long)sd * N + k0 + soct * 8);
      *(uint2*)(&sstage[vdst])       = make_uint2(vl.x, vl.y);
      *(uint2*)(&sstage[vdst + 128]) = make_uint2(vl.z, vl.w);
    }
    __syncthreads();

    f32x4 st[4];
    #pragma unroll
    for (int kb = 0; kb < 4; kb++){
      H8u K;
      K.q = *(const uint4*)(&sstage[ksu + (kb * 64 + lane) * 8]);
      st[kb] = __builtin_amdgcn_mfma_f32_16x16x32_f16(K.h, qf,
                  (f32x4){0.f,0.f,0.f,0.f}, 0, 0, 0);
    }

    float mt = -1e30f;
    #pragma unroll
    for (int kb = 0; kb < 4; kb++)
      #pragma unroll
      for (int r = 0; r < 4; r++){
        st[kb][r] *= SCALE;
        mt = fmaxf(mt, st[kb][r]);
      }
    mt = fmaxf(mt, __shfl_xor(mt, 16));
    mt = fmaxf(mt, __shfl_xor(mt, 32));
    float m_new  = fmaxf(m_run, mt);
    float fscale = __expf(m_run - m_new);
    float lt = 0.f;
    unsigned int pup[8];
    #pragma unroll
    for (int kb = 0; kb < 4; kb++)
      #pragma unroll
      for (int rp = 0; rp < 2; rp++){
        float p0 = __expf(st[kb][2*rp]   - m_new);
        float p1 = __expf(st[kb][2*rp+1] - m_new);
        lt += p0 + p1;
        pup[kb * 2 + rp] = (unsigned int)f2h(p0) | ((unsigned int)f2h(p1) << 16);
      }
    lt += __shfl_xor(lt, 16);
    lt += __shfl_xor(lt, 32);
    l_run = l_run * fscale + lt;
    m_run = m_new;

    float fr[4];
    #pragma unroll
    for (int r = 0; r < 4; r++) fr[r] = __shfl(fscale, lg * 4 + r);
    #pragma unroll
    for (int r = 0; r < 4; r++){ acc0[r] *= fr[r]; acc1[r] *= fr[r]; }

    #pragma unroll
    for (int m = 0; m < 2; m++){
      H8u P, V0, V1;
      P.q.x = pup[4*m]; P.q.y = pup[4*m+1]; P.q.z = pup[4*m+2]; P.q.w = pup[4*m+3];
      V0.q = *(const uint4*)(&sstage[ksu + 2048 + ((m * 2 + 0) * 64 + lane) * 8]);
      V1.q = *(const uint4*)(&sstage[ksu + 2048 + ((m * 2 + 1) * 64 + lane) * 8]);
      acc0 = __builtin_amdgcn_mfma_f32_16x16x32_f16(P.h, V0.h, acc0, 0, 0, 0);
      acc1 = __builtin_amdgcn_mfma_f32_16x16x32_f16(P.h, V1.h, acc1, 0, 0, 0);
    }
  }

  __syncthreads();
  float* accM = smem;
  float* mM   = smem + 8448;
  float* lM   = smem + 8704;
  #pragma unroll
  for (int r = 0; r < 4; r++){
    accM[((qg * 4 + ks) * 16 + (lg * 4 + r)) * 33 + lr]      = acc0[r];
    accM[((qg * 4 + ks) * 16 + (lg * 4 + r)) * 33 + 16 + lr] = acc1[r];
  }
  if (lg == 0){
    mM[(qg * 4 + ks) * 16 + lr] = m_run;
    lM[(qg * 4 + ks) * 16 + lr] = l_run;
  }
  __syncthreads();
  if (ks == 0){
    int q = lane >> 2, dc = lane & 3;
    float ms[4], es[4];
    float m = -1e30f;
    #pragma unroll
    for (int s = 0; s < 4; s++){ ms[s] = mM[(qg * 4 + s) * 16 + q]; m = fmaxf(m, ms[s]); }
    float l = 0.f;
    #pragma unroll
    for (int s = 0; s < 4; s++){ es[s] = __expf(ms[s] - m); l += lM[(qg * 4 + s) * 16 + q] * es[s]; }
    float inv = 1.f / l;
    float o[8];
    #pragma unroll
    for (int j = 0; j < 8; j++) o[j] = 0.f;
    #pragma unroll
    for (int s = 0; s < 4; s++){
      const float* ap = &accM[((qg * 4 + s) * 16 + q) * 33 + dc * 8];
      #pragma unroll
      for (int j = 0; j < 8; j++) o[j] += ap[j] * es[s];
    }
    ushort4 o0, o1;
    o0.x = f2h(o[0]*inv); o0.y = f2h(o[1]*inv); o0.z = f2h(o[2]*inv); o0.w = f2h(o[3]*inv);
    o1.x = f2h(o[4]*inv); o1.y = f2h(o[5]*inv); o1.z = f2h(o[6]*inv); o1.w = f2h(o[7]*inv);
    unsigned short* op = &mhaT[((long)b * N + q0w + q) * 128 + h * 32 + dc * 8];
    *(ushort4*)op = o0;
    *(ushort4*)(op + 4) = o1;
  }
}

// Per-(b,c) sum / sumsq over HW
__global__ void stats_kernel(const float* __restrict__ x, float* __restrict__ sums,
                             float* __restrict__ sumsqs, int HW){
  long bc = blockIdx.x;
  const float* p = x + bc * HW;
  float s = 0.f, s2 = 0.f;
  for (int i = threadIdx.x; i < HW; i += blockDim.x){
    float v = p[i]; s += v; s2 += v * v;
  }
  block_reduce2(s, s2);
  if (threadIdx.x == 0){ sums[bc] = s; sumsqs[bc] = s2; }
}

__global__ void layer_reduce_kernel(const float* __restrict__ sums, const float* __restrict__ sumsqs,
                                    float* __restrict__ lsum, float* __restrict__ lsumsq, int C){
  int b = blockIdx.x;
  float s = 0.f, s2 = 0.f;
  for (int c = threadIdx.x; c < C; c += blockDim.x){
    s += sums[b * C + c]; s2 += sumsqs[b * C + c];
  }
  block_reduce2(s, s2);
  if (threadIdx.x == 0){ lsum[b] = s; lsumsq[b] = s2; }
}

__global__ void iln_finalize_kernel(const float* __restrict__ x,
                                    const float* __restrict__ sums, const float* __restrict__ sumsqs,
                                    const float* __restrict__ lsum, const float* __restrict__ lsumsq,
                                    const float* __restrict__ rho, const float* __restrict__ gamma,
                                    const float* __restrict__ beta,
                                    const float* __restrict__ gate,
                                    float* __restrict__ out,
                                    int HW, int C, int co_off, int Cout_total, int mode){
  int bc = blockIdx.y;
  int b = bc / C, c = bc % C;
  float n = (float)HW;
  float im = sums[bc] / n;
  float iv = (sumsqs[bc] / n - im * im) * (n / (n - 1.f));
  float ir = rsqrtf(iv + EPS);
  float n2 = n * (float)C;
  float lm = lsum[b] / n2;
  float lv = (lsumsq[b] / n2 - lm * lm) * (n2 / (n2 - 1.f));
  float lr = rsqrtf(lv + EPS);
  float r = rho[c], g = gamma[c], bb = beta[c];

  const float* xp = x + (long)bc * HW;
  const float* gp = gate ? gate + (long)bc * HW : nullptr;
  float* op = out + ((long)(b * Cout_total + co_off + c)) * HW;
  for (int i = blockIdx.x * blockDim.x + threadIdx.x; i < HW; i += gridDim.x * blockDim.x){
    float xv = xp[i];
    float t = r * (xv - im) * ir + (1.f - r) * (xv - lm) * lr;
    t = t * g + bb;
    float sg = sigmoidf_(t);
    op[i] = mode ? t * sg : sg * gp[i];
  }
}

extern "C" void kernel_launch(void* const* d_in, const int* in_sizes, int n_in,
                              void* d_out, int out_size, void* d_ws, size_t ws_size,
                              hipStream_t stream){
  const float* y        = (const float*)d_in[0];
  const float* s        = (const float*)d_in[1];
  const float* w_blue_s = (const float*)d_in[2];
  const float* w_blue_y = (const float*)d_in[3];
  const float* w_purple = (const float*)d_in[4];
  const float* rho_p    = (const float*)d_in[5];
  const float* gamma_p  = (const float*)d_in[6];
  const float* beta_p   = (const float*)d_in[7];
  const float* w_green  = (const float*)d_in[8];
  const float* rho_g    = (const float*)d_in[9];
  const float* gamma_g  = (const float*)d_in[10];
  const float* beta_g   = (const float*)d_in[11];
  float* out = (float*)d_out;
  float* ws  = (float*)d_ws;

  const int B = 2, SC = 128, N = 4096, NS = 16384;

  // ---- workspace layout (float units) with overlays ----
  unsigned short* s_peT = (unsigned short*)ws;             // [2][16384][128] fp16
  unsigned short* y_peT = (unsigned short*)(ws + 2097152); // [2][4096][256]  fp16
  unsigned short* yT    = (unsigned short*)(ws + 3145728); // [2][4096][256]  fp16
  float* purple_raw     = ws;                              // [2][128][16384] fp32 (overlays PE bufs)
  float* qbuf       = ws + 4194304;                        // [2][128][4096] fp32
  float* vbuf       = ws + 5242880;                        // [2][128][4096] fp32
  unsigned short* mhaT = (unsigned short*)(ws + 6291456);  // [2][4096][128] fp16
  float* green_raw  = ws + 6815744;                        // [2][128][16384] fp32
  unsigned short* qk_bf = (unsigned short*)green_raw;      // [8][4096][32] fp16 (dead before green)
  unsigned short* v_bf  = qk_bf + 1048576;                 // [2][128][4096] fp16
  // folded upsample weights overlay qbuf (written AFTER in_silu_qk consumes it)
  unsigned short* wffF_green  = (unsigned short*)qbuf;     // 4*8*4*8*512 = 524288
  unsigned short* wffF_purple = wffF_green + 524288;       // 4*8*4*4*512 = 262144
  unsigned short* wffP_blues = (unsigned short*)(ws + 11010048); // 147456
  unsigned short* wffP_bluey = wffP_blues + 147456;        // 294912
  float* stats = ws + 11452416;
  float* sumsG = stats,        *sumsqG = stats + 256;
  float* sumsP = stats + 512,  *sumsqP = stats + 768;
  float* lsumG = stats + 1024, *lsumsqG = stats + 1026;
  float* lsumP = stats + 1028, *lsumsqP = stats + 1030;

  dim3 blk(256);

  // 0) plain fragment-ordered weight repack (blues)
  wffP_kernel<<<dim3(288), blk, 0, stream>>>(w_blue_y, wffP_bluey, 256);
  wffP_kernel<<<dim3(144), blk, 0, stream>>>(w_blue_s, wffP_blues, 128);

  // 1) PE + cast + transpose (and plain cast-transpose of raw y)
  pe_t_kernel<<<dim3(64, 4, B), blk, 0, stream>>>(y, y_peT, 256, N, 128, 1);
  pe_t_kernel<<<dim3(256, 2, B), blk, 0, stream>>>(s, s_peT, 128, NS, 64, 1);
  pe_t_kernel<<<dim3(64, 4, B), blk, 0, stream>>>(y, yT, 256, N, 128, 0);

  // 2) blue convs (MFMA implicit GEMM, 64co x 64sp tiles)
  conv_tile_kernel<9,5,0><<<dim3(64, 2, B), blk, 0, stream>>>(
      y_peT, wffP_bluey, qbuf, 64, 64, 1, 64, 6, 4096);
  conv_tile_kernel<9,4,0><<<dim3(64, 2, B), blk, 0, stream>>>(
      s_peT, wffP_blues, vbuf, 128, 128, 2, 64, 6, 4096);

  // 3) instance norm + SiLU -> fp16 attention layouts
  in_silu_qk_kernel<<<dim3(B * SC), blk, 0, stream>>>(qbuf, qk_bf, N);
  in_silu_v_kernel<<<dim3(B * SC), blk, 0, stream>>>(vbuf, v_bf, N);

  // 3.5) folded upsample weights (into dead qbuf region)
  wffF_kernel<<<dim3(512), blk, 0, stream>>>(w_green,  wffF_green, 256);
  wffF_kernel<<<dim3(256), blk, 0, stream>>>(w_purple, wffF_purple, 128);

  // 4) MFMA flash attention (4-way key split, LDS merge) -> mhaT fp16 [b][N][128]
  flash_attn_kernel<<<dim3(N / 64, B * 4), dim3(1024), 0, stream>>>(qk_bf, v_bf, mhaT, N);

  // 5) green conv: parity-folded upsample 256->128 @128x128
  conv_tile_kernel<4,5,1><<<dim3(64, 2, B * 4), blk, 0, stream>>>(
      yT, wffF_green, green_raw, 64, 64, 1, 128, 7, 16384);

  // 6) purple conv: parity-folded upsample 128->128 @128x128
  conv_tile_kernel<4,4,1><<<dim3(64, 2, B * 4), blk, 0, stream>>>(
      mhaT, wffF_purple, purple_raw, 64, 64, 1, 128, 7, 16384);

  // 7) ILN stats
  stats_kernel<<<dim3(B * SC), blk, 0, stream>>>(green_raw, sumsG, sumsqG, NS);
  stats_kernel<<<dim3(B * SC), blk, 0, stream>>>(purple_raw, sumsP, sumsqP, NS);
  layer_reduce_kernel<<<dim3(B), dim3(64), 0, stream>>>(sumsG, sumsqG, lsumG, lsumsqG, SC);
  layer_reduce_kernel<<<dim3(B), dim3(64), 0, stream>>>(sumsP, sumsqP, lsumP, lsumsqP, SC);

  // 8) finalize
  iln_finalize_kernel<<<dim3(64, B * SC), blk, 0, stream>>>(purple_raw, sumsP, sumsqP,
      lsumP, lsumsqP, rho_p, gamma_p, beta_p, s, out, NS, SC, 0, 256, 0);
  iln_finalize_kernel<<<dim3(64, B * SC), blk, 0, stream>>>(green_raw, sumsG, sumsqG,
      lsumG, lsumsqG, rho_g, gamma_g, beta_g, nullptr, out, NS, SC, 128, 256, 1);
}

// Round 8
// 221.693 us; speedup vs baseline: 22.4132x; 1.1270x over previous
//
#include <hip/hip_runtime.h>
#include <math.h>

#define EPS 1e-5f

typedef __attribute__((ext_vector_type(8))) _Float16 f16x8;
typedef __attribute__((ext_vector_type(4))) float f32x4;
typedef __attribute__((ext_vector_type(2))) __fp16 fp16x2;

union H8u { ushort4 u[2]; uint4 q; f16x8 h; };
union PKu { fp16x2 h; unsigned int u; };

__device__ __forceinline__ float sigmoidf_(float x){ return 1.f/(1.f+__expf(-x)); }

__device__ __forceinline__ unsigned short f2h(float f){
  union { _Float16 h; unsigned short u; } c;
  c.h = (_Float16)f;            // v_cvt_f16_f32, RNE
  return c.u;
}

// block-wide reduction of two accumulators; blockDim.x must be a multiple of 64
__device__ __forceinline__ void block_reduce2(float& s, float& s2){
  __shared__ float ls[16], ls2[16];
  #pragma unroll
  for (int off = 32; off; off >>= 1){
    s  += __shfl_down(s, off);
    s2 += __shfl_down(s2, off);
  }
  int wid = threadIdx.x >> 6, lane = threadIdx.x & 63;
  int nw = blockDim.x >> 6;
  if (lane == 0){ ls[wid] = s; ls2[wid] = s2; }
  __syncthreads();
  if (threadIdx.x == 0){
    float a = ls[0], b = ls2[0];
    for (int i = 1; i < nw; i++){ a += ls[i]; b += ls2[i]; }
    ls[0] = a; ls2[0] = b;
  }
  __syncthreads();
  s = ls[0]; s2 = ls2[0];
}

// Fused (optional PE-add) + fp16 cast + transpose: x [B][C][L] fp32 -> xt [B][L][C] fp16
// Optional second output xt2 = raw (no PE) transposed.
__global__ __launch_bounds__(256) void pe_t_kernel(
    const float* __restrict__ x, unsigned short* __restrict__ xt,
    unsigned short* __restrict__ xt2,
    int C, int L, int half, int addpe){
  __shared__ unsigned short tile[64][72];
  __shared__ unsigned short tile2[64][72];
  int b = blockIdx.z;
  int c0 = blockIdx.y * 64, l0 = blockIdx.x * 64;
  int tid = threadIdx.x;
  const float l2r = 13.28771237954945f; // log2(10000)
  #pragma unroll
  for (int i = 0; i < 4; i++){
    int id = tid + i * 256;
    int c = id >> 4, ch = (id & 15) * 4;
    int cg = c0 + c;
    float4 v = *(const float4*)&x[((long)b * C + cg) * L + l0 + ch];
    float pe0 = 0.f, pe1 = 0.f, pe2 = 0.f, pe3 = 0.f;
    if (addpe){
      int d = cg < half ? cg : cg - half;
      float rate = exp2f(-l2r * (float)d / (float)half);
      float a0 = (float)(l0 + ch) * rate;
      if (cg < half){ pe0 = sinf(a0); pe1 = sinf(a0 + rate); pe2 = sinf(a0 + 2.f*rate); pe3 = sinf(a0 + 3.f*rate); }
      else          { pe0 = cosf(a0); pe1 = cosf(a0 + rate); pe2 = cosf(a0 + 2.f*rate); pe3 = cosf(a0 + 3.f*rate); }
    }
    ushort4 o;
    o.x = f2h(v.x + pe0); o.y = f2h(v.y + pe1);
    o.z = f2h(v.z + pe2); o.w = f2h(v.w + pe3);
    *(ushort4*)&tile[c][ch] = o;
    if (xt2){
      ushort4 o2;
      o2.x = f2h(v.x); o2.y = f2h(v.y); o2.z = f2h(v.z); o2.w = f2h(v.w);
      *(ushort4*)&tile2[c][ch] = o2;
    }
  }
  __syncthreads();
  #pragma unroll
  for (int i = 0; i < 2; i++){
    int id = tid + i * 256;
    int l = id >> 3, ch = (id & 7) * 8;
    ushort4 a, bq;
    a.x = tile[ch+0][l]; a.y = tile[ch+1][l]; a.z = tile[ch+2][l]; a.w = tile[ch+3][l];
    bq.x = tile[ch+4][l]; bq.y = tile[ch+5][l]; bq.z = tile[ch+6][l]; bq.w = tile[ch+7][l];
    unsigned short* op = &xt[((long)b * L + l0 + l) * C + c0 + ch];
    *(ushort4*)op = a;
    *(ushort4*)(op + 4) = bq;
    if (xt2){
      ushort4 a2, b2;
      a2.x = tile2[ch+0][l]; a2.y = tile2[ch+1][l]; a2.z = tile2[ch+2][l]; a2.w = tile2[ch+3][l];
      b2.x = tile2[ch+4][l]; b2.y = tile2[ch+5][l]; b2.z = tile2[ch+6][l]; b2.w = tile2[ch+7][l];
      unsigned short* op2 = &xt2[((long)b * L + l0 + l) * C + c0 + ch];
      *(ushort4*)op2 = a2;
      *(ushort4*)(op2 + 4) = b2;
    }
  }
}

// Plain weights -> fragment-ordered fp16: [coB(8)][9][NCHUNK][64 lanes][8]
__global__ void wffP_kernel(const float* __restrict__ w, unsigned short* __restrict__ o, int Cin){
  int NCH = Cin >> 5;
  int per_tap = NCH << 9;
  int total = 8 * 9 * per_tap;
  for (int idx = blockIdx.x * blockDim.x + threadIdx.x; idx < total;
       idx += gridDim.x * blockDim.x){
    int e = idx & 7, lane = (idx >> 3) & 63, chunk = (idx >> 9) % NCH;
    int tap = (idx / per_tap) % 9, coB = idx / (9 * per_tap);
    int lg = lane >> 4, lr = lane & 15;
    int co = coB * 16 + lr;
    int ch = chunk * 32 + ((e < 4) ? lg * 4 + e : 16 + lg * 4 + e - 4);
    o[idx] = f2h(w[((long)co * Cin + ch) * 9 + tap]);
  }
}

// Parity-folded upsample weights -> fragment order: [p(4)][coB(8)][4 tap][NCHUNK][64][8]
__global__ void wffF_kernel(const float* __restrict__ w, unsigned short* __restrict__ o, int Cin){
  int NCH = Cin >> 5;
  int per_tap = NCH << 9;
  int per_p = 8 * 4 * per_tap;
  int total = 4 * per_p;
  for (int idx = blockIdx.x * blockDim.x + threadIdx.x; idx < total;
       idx += gridDim.x * blockDim.x){
    int e = idx & 7, lane = (idx >> 3) & 63, chunk = (idx >> 9) % NCH;
    int tap = (idx / per_tap) % 4;
    int coB = (idx / (4 * per_tap)) % 8;
    int p = idx / per_p;
    int ph = p >> 1, pw = p & 1, kr = tap >> 1, kc = tap & 1;
    int lg = lane >> 4, lr = lane & 15;
    int co = coB * 16 + lr;
    int ch = chunk * 32 + ((e < 4) ? lg * 4 + e : 16 + lg * 4 + e - 4);
    const float* wb = &w[((long)co * Cin + ch) * 9];
    float sum = 0.f;
    for (int kh = 0; kh < 3; kh++){
      bool rok = (ph == 0) ? (kr == 0 ? kh == 0 : kh >= 1)
                           : (kr == 0 ? kh <= 1 : kh == 2);
      if (!rok) continue;
      for (int kw = 0; kw < 3; kw++){
        bool cok = (pw == 0) ? (kc == 0 ? kw == 0 : kw >= 1)
                             : (kc == 0 ? kw <= 1 : kw == 2);
        if (cok) sum += wb[kh * 3 + kw];
      }
    }
    o[idx] = f2h(sum);
  }
}

// Unified implicit-GEMM MFMA conv (fp16 output). Block = 4 waves, 64co x 64sp.
template<int NTAP, int CSHIFT, int UP>
__global__ __launch_bounds__(256) void conv_tile_kernel(
    const unsigned short* __restrict__ xt, const unsigned short* __restrict__ wff,
    unsigned short* __restrict__ out,
    int Hin, int Win, int stride, int Wout, int woutLog, int HWout){
  constexpr int Cin = 8 << CSHIFT;
  constexpr int NCHUNK = 1 << (CSHIFT - 2);
  __shared__ __align__(16) char stage[NCHUNK * 4112];
  __shared__ int rowIdx[NTAP][64];
  int tid = threadIdx.x;
  int lane = tid & 63, wid = tid >> 6;
  int lg = lane >> 4, lr = lane & 15;
  int b, par = 0;
  if (UP){ par = blockIdx.z & 3; b = blockIdx.z >> 2; } else b = blockIdx.z;
  const unsigned short* xb = xt + (long)b * Hin * Win * Cin;
  int coB = blockIdx.y * 4 + wid;

  if (UP){
    int ph = par >> 1, pw = par & 1;
    int ii = blockIdx.x;
    int VH = 2 * Hin, VW = 2 * Win;
    for (int id = tid; id < NTAP * 64; id += 256){
      int tap = id >> 6, r = id & 63;
      int kr = tap >> 1, kc = tap & 1;
      int v = 2 * ii + (ph == 0 ? (kr == 0 ? -1 : 0) : (kr == 0 ? 0 : 2));
      v = v < 0 ? -v : (v >= VH ? 2 * VH - 2 - v : v);
      int u = 2 * r + (pw == 0 ? (kc == 0 ? -1 : 0) : (kc == 0 ? 0 : 2));
      u = u < 0 ? -u : (u >= VW ? 2 * VW - 2 - u : u);
      rowIdx[tap][r] = (v >> 1) * Win + (u >> 1);
    }
  } else {
    int sp0 = blockIdx.x * 64;
    for (int id = tid; id < NTAP * 64; id += 256){
      int tap = id >> 6, r = id & 63;
      int kh = tap / 3, kw = tap - kh * 3;
      int sp = sp0 + r;
      int oh = sp >> woutLog, ow = sp & (Wout - 1);
      int ih = oh * stride - 1 + kh;
      ih = ih < 0 ? -ih : (ih >= Hin ? 2 * Hin - 2 - ih : ih);
      int iw = ow * stride - 1 + kw;
      iw = iw < 0 ? -iw : (iw >= Win ? 2 * Win - 2 - iw : iw);
      rowIdx[tap][r] = ih * Win + iw;
    }
  }

  f32x4 acc[4];
  #pragma unroll
  for (int f = 0; f < 4; f++) acc[f] = (f32x4){0.f, 0.f, 0.f, 0.f};

  const unsigned short* wbase =
      wff + ((long)((UP ? par : 0) * 8 + coB) * NTAP) * (NCHUNK * 512) + lane * 8;

  for (int tap = 0; tap < NTAP; tap++){
    __syncthreads();
    #pragma unroll
    for (int i2 = 0; i2 < NCHUNK; i2++){
      int id = tid + (i2 << 8);
      int sp = id >> CSHIFT;
      int c8 = (id & ((1 << CSHIFT) - 1)) << 3;
      int chunk = c8 >> 5, c = c8 & 31;
      int lgb = (c & 15) >> 2, hoff = (c >> 4) & 1;
      uint4 g = *(const uint4*)&xb[(long)rowIdx[tap][sp] * Cin + c8];
      int slot = ((chunk * 4 + (sp >> 4)) * 64 + lgb * 16 + (sp & 15)) * 16
                 + hoff * 8 + chunk * 16;
      *(uint2*)(stage + slot)       = make_uint2(g.x, g.y);
      *(uint2*)(stage + slot + 256) = make_uint2(g.z, g.w);
    }
    __syncthreads();
    const unsigned short* wp = wbase + (long)tap * (NCHUNK * 512);
    #pragma unroll
    for (int ch = 0; ch < NCHUNK; ch++){
      H8u A; A.q = *(const uint4*)(wp + ch * 512);
      #pragma unroll
      for (int f = 0; f < 4; f++){
        H8u X; X.q = *(const uint4*)(stage + ((ch * 4 + f) * 64 + lane) * 16 + ch * 16);
        acc[f] = __builtin_amdgcn_mfma_f32_16x16x32_f16(A.h, X.h, acc[f], 0, 0, 0);
      }
    }
  }

  unsigned short* ob = out + (long)b * 128 * HWout;
  #pragma unroll
  for (int f = 0; f < 4; f++){
    int spl = f * 16 + lr;
    long opos;
    if (UP){
      int oh = 2 * blockIdx.x + (par >> 1);
      int ow = 2 * spl + (par & 1);
      opos = (long)oh * Wout + ow;
    } else opos = (long)blockIdx.x * 64 + spl;
    #pragma unroll
    for (int r = 0; r < 4; r++){
      int co = coB * 16 + lg * 4 + r;
      ob[(long)co * HWout + opos] = f2h(acc[f][r]);
    }
  }
}

// InstanceNorm+SiLU from fp16, output fp16 TRANSPOSED for Q/K: outT[bh][pos][32]
__global__ __launch_bounds__(256) void in_silu_qk_kernel(
    const unsigned short* __restrict__ x, unsigned short* __restrict__ outT, int HW){
  int bc = blockIdx.x;
  const unsigned short* p = x + (long)bc * HW;
  int i0 = threadIdx.x * 16;
  H8u a, b2;
  a.q  = *(const uint4*)&p[i0];
  b2.q = *(const uint4*)&p[i0 + 8];
  float v[16];
  float s = 0.f, s2 = 0.f;
  #pragma unroll
  for (int j = 0; j < 8; j++){ v[j] = (float)a.h[j]; v[8+j] = (float)b2.h[j]; }
  #pragma unroll
  for (int j = 0; j < 16; j++){ s += v[j]; s2 += v[j]*v[j]; }
  block_reduce2(s, s2);
  float mean = s / (float)HW;
  float var  = s2 / (float)HW - mean * mean;
  float rstd = rsqrtf(var + EPS);
  int b = bc >> 7, cg = bc & 127, h = cg >> 5, d = cg & 31;
  unsigned short* op = outT + ((long)(b * 4 + h) * HW) * 32 + d;
  #pragma unroll
  for (int j = 0; j < 16; j++){
    float t = (v[j] - mean) * rstd;
    t = t * sigmoidf_(t);
    op[(long)(i0 + j) * 32] = f2h(t);
  }
}

// InstanceNorm+SiLU from fp16, output fp16 channel-major (= V^T per head slice)
__global__ __launch_bounds__(256) void in_silu_v_kernel(
    const unsigned short* __restrict__ x, unsigned short* __restrict__ out, int HW){
  int bc = blockIdx.x;
  const unsigned short* p = x + (long)bc * HW;
  int i0 = threadIdx.x * 16;
  H8u a, b2;
  a.q  = *(const uint4*)&p[i0];
  b2.q = *(const uint4*)&p[i0 + 8];
  float v[16];
  float s = 0.f, s2 = 0.f;
  #pragma unroll
  for (int j = 0; j < 8; j++){ v[j] = (float)a.h[j]; v[8+j] = (float)b2.h[j]; }
  #pragma unroll
  for (int j = 0; j < 16; j++){ s += v[j]; s2 += v[j]*v[j]; }
  block_reduce2(s, s2);
  float mean = s / (float)HW;
  float var  = s2 / (float)HW - mean * mean;
  float rstd = rsqrtf(var + EPS);
  H8u o0, o1;
  #pragma unroll
  for (int j = 0; j < 8; j++){
    float t = (v[j] - mean) * rstd;
    o0.h[j] = (_Float16)(t * sigmoidf_(t));
    float t1 = (v[8+j] - mean) * rstd;
    o1.h[j] = (_Float16)(t1 * sigmoidf_(t1));
  }
  unsigned short* op = out + (long)bc * HW + i0;
  *(uint4*)op = o0.q;
  *(uint4*)(op + 8) = o1.q;
}

// MFMA flash attention (fp16), 4-way key-split, 128-key tiles, fragment-slot staging.
// qk [bh][N][32]; v [b*128+c][N]; out mhaT fp16 [b][N][128].
__global__ __launch_bounds__(1024, 8) void flash_attn_kernel(
    const unsigned short* __restrict__ qk,
    const unsigned short* __restrict__ vt,
    unsigned short* __restrict__ mhaT, int N){
  __shared__ float smem[16384];                // 64 KB: 4 splits x 1024 slots x 16B
  unsigned short* sstage = (unsigned short*)smem;
  const float SCALE2 = 0.25503257066404493f;   // (1/sqrt(32)) * log2(e)

  int bh = blockIdx.y;
  int b = bh >> 2, h = bh & 3;
  int tid = threadIdx.x;
  int ks = tid >> 8;
  int t256 = tid & 255;
  int qg = (tid >> 6) & 3;
  int lane = tid & 63;
  int lg = lane >> 4, lr = lane & 15;
  const unsigned short* qbase = qk + (long)bh * N * 32;
  const unsigned short* vbase = vt + (long)(b * 128 + h * 32) * N;
  int ksl = ks << 10;                          // slot base per split

  int q0w = blockIdx.x * 64 + qg * 16;
  f16x8 qf;
  {
    const unsigned short* qp = qbase + (long)(q0w + lr) * 32 + lg * 4;
    H8u Q;
    Q.u[0] = *(const ushort4*)qp;
    Q.u[1] = *(const ushort4*)(qp + 16);
    qf = Q.h;
  }

  // staging: t256<128 -> K row (key=krow, 64B); else V (d=krow>>2, m-key-block=krow&3, 64B)
  int krow = t256 & 127;
  bool isK = t256 < 128;
  const unsigned short* stbase;
  int s0;
  if (isK){
    stbase = qbase + (long)krow * 32;
    s0 = ksl + ((krow >> 4) << 6) + (krow & 15);
  } else {
    int d = krow >> 2, m = krow & 3;
    stbase = vbase + (long)d * N + m * 32;
    s0 = ksl + 512 + (((m << 1) + (d >> 4)) << 6) + (d & 15);
  }

  float m_run = -1e30f, l_run = 0.f;
  f32x4 acc0 = {0.f,0.f,0.f,0.f}, acc1 = {0.f,0.f,0.f,0.f};

  const int NT = N >> 9;                       // 128-key tiles per split
  for (int t = 0; t < NT; t++){
    int k0 = (ks << 10) + (t << 7);
    __syncthreads();
    {
      const unsigned short* sp = stbase + (isK ? ((long)k0 << 5) : (long)k0);
      uint4 q0 = *(const uint4*)sp;
      uint4 q1 = *(const uint4*)(sp + 8);
      uint4 q2 = *(const uint4*)(sp + 16);
      uint4 q3 = *(const uint4*)(sp + 24);
      *(uint4*)(sstage + (long)(s0     ) * 8) = make_uint4(q0.x, q0.y, q2.x, q2.y);
      *(uint4*)(sstage + (long)(s0 + 16) * 8) = make_uint4(q0.z, q0.w, q2.z, q2.w);
      *(uint4*)(sstage + (long)(s0 + 32) * 8) = make_uint4(q1.x, q1.y, q3.x, q3.y);
      *(uint4*)(sstage + (long)(s0 + 48) * 8) = make_uint4(q1.z, q1.w, q3.z, q3.w);
    }
    __syncthreads();

    #pragma unroll
    for (int p = 0; p < 2; p++){
      f32x4 st[4];
      #pragma unroll
      for (int kb = 0; kb < 4; kb++){
        H8u K;
        K.q = *(const uint4*)(sstage + (long)(ksl + ((p*4+kb) << 6) + lane) * 8);
        st[kb] = __builtin_amdgcn_mfma_f32_16x16x32_f16(K.h, qf,
                    (f32x4){0.f,0.f,0.f,0.f}, 0, 0, 0);
      }

      float mt = -1e30f;
      #pragma unroll
      for (int kb = 0; kb < 4; kb++)
        #pragma unroll
        for (int r = 0; r < 4; r++){
          st[kb][r] *= SCALE2;
          mt = fmaxf(mt, st[kb][r]);
        }
      mt = fmaxf(mt, __shfl_xor(mt, 16));
      mt = fmaxf(mt, __shfl_xor(mt, 32));
      float m_new  = fmaxf(m_run, mt);
      float fscale = __builtin_amdgcn_exp2f(m_run - m_new);
      float lt = 0.f;
      unsigned int pup[8];
      #pragma unroll
      for (int kb = 0; kb < 4; kb++)
        #pragma unroll
        for (int rp = 0; rp < 2; rp++){
          float p0 = __builtin_amdgcn_exp2f(st[kb][2*rp]   - m_new);
          float p1 = __builtin_amdgcn_exp2f(st[kb][2*rp+1] - m_new);
          lt += p0 + p1;
          PKu pk;
          pk.h = __builtin_amdgcn_cvt_pkrtz(p0, p1);
          pup[kb * 2 + rp] = pk.u;
        }
      lt += __shfl_xor(lt, 16);
      lt += __shfl_xor(lt, 32);
      l_run = l_run * fscale + lt;
      m_run = m_new;

      float fr[4];
      #pragma unroll
      for (int r = 0; r < 4; r++) fr[r] = __shfl(fscale, lg * 4 + r);
      #pragma unroll
      for (int r = 0; r < 4; r++){ acc0[r] *= fr[r]; acc1[r] *= fr[r]; }

      #pragma unroll
      for (int mm = 0; mm < 2; mm++){
        int m = p * 2 + mm;
        H8u P, V0, V1;
        P.q = make_uint4(pup[4*mm], pup[4*mm+1], pup[4*mm+2], pup[4*mm+3]);
        V0.q = *(const uint4*)(sstage + (long)(ksl + 512 + ((m*2    ) << 6) + lane) * 8);
        V1.q = *(const uint4*)(sstage + (long)(ksl + 512 + ((m*2 + 1) << 6) + lane) * 8);
        acc0 = __builtin_amdgcn_mfma_f32_16x16x32_f16(P.h, V0.h, acc0, 0, 0, 0);
        acc1 = __builtin_amdgcn_mfma_f32_16x16x32_f16(P.h, V1.h, acc1, 0, 0, 0);
      }
    }
  }

  // ---- split merge in LDS ----
  __syncthreads();
  float* accM = smem;                          // [qg][ks][16 q][33]
  float* mM   = smem + 8448;
  float* lM   = smem + 8704;
  #pragma unroll
  for (int r = 0; r < 4; r++){
    accM[((qg * 4 + ks) * 16 + (lg * 4 + r)) * 33 + lr]      = acc0[r];
    accM[((qg * 4 + ks) * 16 + (lg * 4 + r)) * 33 + 16 + lr] = acc1[r];
  }
  if (lg == 0){
    mM[(qg * 4 + ks) * 16 + lr] = m_run;
    lM[(qg * 4 + ks) * 16 + lr] = l_run;
  }
  __syncthreads();
  if (ks == 0){
    int q = lane >> 2, dc = lane & 3;
    float ms[4], es[4];
    float m = -1e30f;
    #pragma unroll
    for (int s = 0; s < 4; s++){ ms[s] = mM[(qg * 4 + s) * 16 + q]; m = fmaxf(m, ms[s]); }
    float l = 0.f;
    #pragma unroll
    for (int s = 0; s < 4; s++){
      es[s] = __builtin_amdgcn_exp2f(ms[s] - m);
      l += lM[(qg * 4 + s) * 16 + q] * es[s];
    }
    float inv = 1.f / l;
    float o[8];
    #pragma unroll
    for (int j = 0; j < 8; j++) o[j] = 0.f;
    #pragma unroll
    for (int s = 0; s < 4; s++){
      const float* ap = &accM[((qg * 4 + s) * 16 + q) * 33 + dc * 8];
      #pragma unroll
      for (int j = 0; j < 8; j++) o[j] += ap[j] * es[s];
    }
    ushort4 o0, o1;
    o0.x = f2h(o[0]*inv); o0.y = f2h(o[1]*inv); o0.z = f2h(o[2]*inv); o0.w = f2h(o[3]*inv);
    o1.x = f2h(o[4]*inv); o1.y = f2h(o[5]*inv); o1.z = f2h(o[6]*inv); o1.w = f2h(o[7]*inv);
    unsigned short* op = &mhaT[((long)b * N + q0w + q) * 128 + h * 32 + dc * 8];
    *(ushort4*)op = o0;
    *(ushort4*)(op + 4) = o1;
  }
}

// Per-(b,c) sum / sumsq over HW (fp16 input)
__global__ __launch_bounds__(256) void stats_kernel(
    const unsigned short* __restrict__ x, float* __restrict__ sums,
    float* __restrict__ sumsqs, int HW){
  long bc = blockIdx.x;
  const unsigned short* p = x + bc * HW;
  float s = 0.f, s2 = 0.f;
  for (int i = threadIdx.x * 8; i < HW; i += 256 * 8){
    H8u a; a.q = *(const uint4*)&p[i];
    #pragma unroll
    for (int j = 0; j < 8; j++){ float f = (float)a.h[j]; s += f; s2 += f * f; }
  }
  block_reduce2(s, s2);
  if (threadIdx.x == 0){ sums[bc] = s; sumsqs[bc] = s2; }
}

__global__ void layer_reduce_kernel(const float* __restrict__ sums, const float* __restrict__ sumsqs,
                                    float* __restrict__ lsum, float* __restrict__ lsumsq, int C){
  int b = blockIdx.x;
  float s = 0.f, s2 = 0.f;
  for (int c = threadIdx.x; c < C; c += blockDim.x){
    s += sums[b * C + c]; s2 += sumsqs[b * C + c];
  }
  block_reduce2(s, s2);
  if (threadIdx.x == 0){ lsum[b] = s; lsumsq[b] = s2; }
}

// ILN + affine + activation from fp16 x; mode 0: sigmoid*gate, mode 1: silu.
__global__ __launch_bounds__(256) void iln_finalize_kernel(
    const unsigned short* __restrict__ x,
    const float* __restrict__ sums, const float* __restrict__ sumsqs,
    const float* __restrict__ lsum, const float* __restrict__ lsumsq,
    const float* __restrict__ rho, const float* __restrict__ gamma,
    const float* __restrict__ beta,
    const float* __restrict__ gate,
    float* __restrict__ out,
    int HW, int C, int co_off, int Cout_total, int mode){
  int bc = blockIdx.y;
  int b = bc / C, c = bc % C;
  float n = (float)HW;
  float im = sums[bc] / n;
  float iv = (sumsqs[bc] / n - im * im) * (n / (n - 1.f));
  float ir = rsqrtf(iv + EPS);
  float n2 = n * (float)C;
  float lm = lsum[b] / n2;
  float lv = (lsumsq[b] / n2 - lm * lm) * (n2 / (n2 - 1.f));
  float lr = rsqrtf(lv + EPS);
  float r = rho[c], g = gamma[c], bb = beta[c];

  const unsigned short* xp = x + (long)bc * HW;
  const float* gp = gate ? gate + (long)bc * HW : nullptr;
  float* op = out + ((long)(b * Cout_total + co_off + c)) * HW;
  int i0 = (blockIdx.x * 256 + threadIdx.x) * 8;
  H8u a; a.q = *(const uint4*)&xp[i0];
  float4 o0, o1;
  float res[8];
  #pragma unroll
  for (int j = 0; j < 8; j++){
    float xv = (float)a.h[j];
    float t = r * (xv - im) * ir + (1.f - r) * (xv - lm) * lr;
    t = t * g + bb;
    float sg = sigmoidf_(t);
    res[j] = mode ? t * sg : sg;
  }
  if (!mode){
    float4 g0 = *(const float4*)&gp[i0];
    float4 g1 = *(const float4*)&gp[i0 + 4];
    res[0] *= g0.x; res[1] *= g0.y; res[2] *= g0.z; res[3] *= g0.w;
    res[4] *= g1.x; res[5] *= g1.y; res[6] *= g1.z; res[7] *= g1.w;
  }
  o0.x = res[0]; o0.y = res[1]; o0.z = res[2]; o0.w = res[3];
  o1.x = res[4]; o1.y = res[5]; o1.z = res[6]; o1.w = res[7];
  *(float4*)&op[i0] = o0;
  *(float4*)&op[i0 + 4] = o1;
}

extern "C" void kernel_launch(void* const* d_in, const int* in_sizes, int n_in,
                              void* d_out, int out_size, void* d_ws, size_t ws_size,
                              hipStream_t stream){
  const float* y        = (const float*)d_in[0];
  const float* s        = (const float*)d_in[1];
  const float* w_blue_s = (const float*)d_in[2];
  const float* w_blue_y = (const float*)d_in[3];
  const float* w_purple = (const float*)d_in[4];
  const float* rho_p    = (const float*)d_in[5];
  const float* gamma_p  = (const float*)d_in[6];
  const float* beta_p   = (const float*)d_in[7];
  const float* w_green  = (const float*)d_in[8];
  const float* rho_g    = (const float*)d_in[9];
  const float* gamma_g  = (const float*)d_in[10];
  const float* beta_g   = (const float*)d_in[11];
  float* out = (float*)d_out;
  float* ws  = (float*)d_ws;

  const int B = 2, SC = 128, N = 4096, NS = 16384;

  // ---- workspace layout (float units) ----
  unsigned short* s_peT = (unsigned short*)ws;                   // 0..2097152 (dead after blue_s)
  unsigned short* y_peT = (unsigned short*)(ws + 2097152);       // ..3145728
  unsigned short* yT    = (unsigned short*)(ws + 3145728);       // ..4194304 (dead after green)
  unsigned short* purple_h = (unsigned short*)ws;                // overlays s_peT
  unsigned short* qbuf_h = (unsigned short*)(ws + 4194304);      // ..4718592
  unsigned short* vbuf_h = (unsigned short*)(ws + 4718592);      // ..5242880
  unsigned short* mhaT   = (unsigned short*)(ws + 5242880);      // ..5767168
  unsigned short* qk_bf  = (unsigned short*)(ws + 5767168);      // ..6291456
  unsigned short* v_bf   = (unsigned short*)(ws + 6291456);      // ..6815744
  unsigned short* green_h = (unsigned short*)(ws + 6815744);     // ..8912896
  unsigned short* wffP_blues = (unsigned short*)(ws + 8912896);  // 147456 ushort
  unsigned short* wffP_bluey = (unsigned short*)(ws + 8986624);  // 294912 ushort
  unsigned short* wffF_green = (unsigned short*)(ws + 9134080);  // 524288 ushort
  unsigned short* wffF_purple = (unsigned short*)(ws + 9396224); // 262144 ushort
  float* stats = ws + 9527296;
  float* sumsG = stats,        *sumsqG = stats + 256;
  float* sumsP = stats + 512,  *sumsqP = stats + 768;
  float* lsumG = stats + 1024, *lsumsqG = stats + 1026;
  float* lsumP = stats + 1028, *lsumsqP = stats + 1030;

  dim3 blk(256);

  // 0) weight preps (all independent)
  wffP_kernel<<<dim3(288), blk, 0, stream>>>(w_blue_y, wffP_bluey, 256);
  wffP_kernel<<<dim3(144), blk, 0, stream>>>(w_blue_s, wffP_blues, 128);
  wffF_kernel<<<dim3(512), blk, 0, stream>>>(w_green,  wffF_green, 256);
  wffF_kernel<<<dim3(256), blk, 0, stream>>>(w_purple, wffF_purple, 128);

  // 1) PE + cast + transpose (y: dual output PE'd + raw)
  pe_t_kernel<<<dim3(64, 4, B), blk, 0, stream>>>(y, y_peT, yT, 256, N, 128, 1);
  pe_t_kernel<<<dim3(256, 2, B), blk, 0, stream>>>(s, s_peT, nullptr, 128, NS, 64, 1);

  // 2) blue convs -> fp16
  conv_tile_kernel<9,5,0><<<dim3(64, 2, B), blk, 0, stream>>>(
      y_peT, wffP_bluey, qbuf_h, 64, 64, 1, 64, 6, 4096);
  conv_tile_kernel<9,4,0><<<dim3(64, 2, B), blk, 0, stream>>>(
      s_peT, wffP_blues, vbuf_h, 128, 128, 2, 64, 6, 4096);

  // 3) instance norm + SiLU -> fp16 attention layouts
  in_silu_qk_kernel<<<dim3(B * SC), blk, 0, stream>>>(qbuf_h, qk_bf, N);
  in_silu_v_kernel<<<dim3(B * SC), blk, 0, stream>>>(vbuf_h, v_bf, N);

  // 4) MFMA flash attention -> mhaT fp16 [b][N][128]
  flash_attn_kernel<<<dim3(N / 64, B * 4), dim3(1024), 0, stream>>>(qk_bf, v_bf, mhaT, N);

  // 5) green conv: parity-folded upsample 256->128 @128x128 -> fp16
  conv_tile_kernel<4,5,1><<<dim3(64, 2, B * 4), blk, 0, stream>>>(
      yT, wffF_green, green_h, 64, 64, 1, 128, 7, 16384);

  // 6) purple conv: parity-folded upsample 128->128 @128x128 -> fp16 (overlays PE region)
  conv_tile_kernel<4,4,1><<<dim3(64, 2, B * 4), blk, 0, stream>>>(
      mhaT, wffF_purple, purple_h, 64, 64, 1, 128, 7, 16384);

  // 7) ILN stats
  stats_kernel<<<dim3(B * SC), blk, 0, stream>>>(green_h, sumsG, sumsqG, NS);
  stats_kernel<<<dim3(B * SC), blk, 0, stream>>>(purple_h, sumsP, sumsqP, NS);
  layer_reduce_kernel<<<dim3(B), dim3(64), 0, stream>>>(sumsG, sumsqG, lsumG, lsumsqG, SC);
  layer_reduce_kernel<<<dim3(B), dim3(64), 0, stream>>>(sumsP, sumsqP, lsumP, lsumsqP, SC);

  // 8) finalize
  iln_finalize_kernel<<<dim3(8, B * SC), blk, 0, stream>>>(purple_h, sumsP, sumsqP,
      lsumP, lsumsqP, rho_p, gamma_p, beta_p, s, out, NS, SC, 0, 256, 0);
  iln_finalize_kernel<<<dim3(8, B * SC), blk, 0, stream>>>(green_h, sumsG, sumsqG,
      lsumG, lsumsqG, rho_g, gamma_g, beta_g, nullptr, out, NS, SC, 128, 256, 1);
}